// Round 1
// baseline (214.165 us; speedup 1.0000x reference)
//
#include <hip/hip_runtime.h>
#include <math.h>

// Problem constants
#define B_ 2
#define T_ 1024
#define D_ 512
#define H_ 8
#define DK_ 64
#define NBH_ 16          // B*H
#define C_ 32            // chunk length
#define G_ 32            // T/C chunks
#define M_ 2048          // B*T rows

#define PI_OVER_2T 0.00153398078788564122971808758949f  /* pi/2048 as float */

// ---------------------------------------------------------------------------
// Kernel 1: fused projection GEMM.  Y = act(x @ W) for W in {Wq,Wk,Wv,Wg}.
// x: (2048,512), each W: (512,512).  Tile 128x128, 8x8 microtile, BK=16.
// grid: (16 col-tiles, 16 row-tiles); which matrix = colTile>>2.
// ---------------------------------------------------------------------------
__global__ __launch_bounds__(256) void k_proj(
    const float* __restrict__ x, const float* __restrict__ Wq,
    const float* __restrict__ Wk, const float* __restrict__ Wv,
    const float* __restrict__ Wg, const float* __restrict__ bg,
    float* __restrict__ Qo, float* __restrict__ Ko,
    float* __restrict__ Vo, float* __restrict__ Go)
{
    __shared__ __align__(16) float AsT[16][132];  // [k][row], pad 132 (2-way max)
    __shared__ __align__(16) float Bs[16][132];   // [k][col]

    const int ct = blockIdx.x;           // 0..15
    const int rt = blockIdx.y;           // 0..15
    const int which = ct >> 2;
    const int jBase = (ct & 3) * 128;
    const float* __restrict__ W = (which == 0) ? Wq : (which == 1) ? Wk
                                 : (which == 2) ? Wv : Wg;
    const int tid = threadIdx.x;
    const int ty = tid >> 4, tx = tid & 15;
    const int rBase = rt * 128;

    float acc[8][8];
#pragma unroll
    for (int i = 0; i < 8; i++)
#pragma unroll
        for (int j = 0; j < 8; j++) acc[i][j] = 0.f;

    const int ar0 = tid >> 2;            // 0..63 (A rows, +64 second half)
    const int ak4 = (tid & 3) * 4;       // 0,4,8,12
    const int bk0 = tid >> 5;            // 0..7 (B k-rows, +8 second half)
    const int bc4 = (tid & 31) * 4;      // 0..124

    for (int kb = 0; kb < 512; kb += 16) {
        __syncthreads();
#pragma unroll
        for (int rr = 0; rr < 2; rr++) {
            int ar = ar0 + rr * 64;
            float4 av = *(const float4*)&x[(size_t)(rBase + ar) * D_ + kb + ak4];
            AsT[ak4 + 0][ar] = av.x; AsT[ak4 + 1][ar] = av.y;
            AsT[ak4 + 2][ar] = av.z; AsT[ak4 + 3][ar] = av.w;
        }
#pragma unroll
        for (int rr = 0; rr < 2; rr++) {
            int bk = bk0 + rr * 8;
            *(float4*)&Bs[bk][bc4] =
                *(const float4*)&W[(size_t)(kb + bk) * D_ + jBase + bc4];
        }
        __syncthreads();
#pragma unroll
        for (int k = 0; k < 16; k++) {
            float a[8], b[8];
            *(float4*)&a[0] = *(const float4*)&AsT[k][ty * 4];
            *(float4*)&a[4] = *(const float4*)&AsT[k][64 + ty * 4];
            *(float4*)&b[0] = *(const float4*)&Bs[k][tx * 4];
            *(float4*)&b[4] = *(const float4*)&Bs[k][64 + tx * 4];
#pragma unroll
            for (int i = 0; i < 8; i++)
#pragma unroll
                for (int j = 0; j < 8; j++) acc[i][j] += a[i] * b[j];
        }
    }

    float* __restrict__ Out = (which == 0) ? Qo : (which == 1) ? Ko
                             : (which == 2) ? Vo : Go;
#pragma unroll
    for (int i = 0; i < 8; i++) {
        int r = rBase + ((i < 4) ? (ty * 4 + i) : (64 + ty * 4 + (i - 4)));
#pragma unroll
        for (int jg = 0; jg < 2; jg++) {
            float vv[4];
#pragma unroll
            for (int u = 0; u < 4; u++) {
                int j = jg * 4 + u;
                int col = jBase + jg * 64 + tx * 4 + u;
                float val = acc[i][j];
                if (which <= 1) val = fmaxf(val, 0.f);
                else if (which == 3) val = 1.f / (1.f + expf(-(val + bg[col])));
                vv[u] = val;
            }
            int colBase = jBase + jg * 64 + tx * 4;
            *(float4*)&Out[(size_t)r * D_ + colBase] =
                make_float4(vv[0], vv[1], vv[2], vv[3]);
        }
    }
}

// ---------------------------------------------------------------------------
// Kernel 2: per-chunk KV outer-product local sums.
// block = (bh, g).  Sc_local[d][e] = sum_t Kc[t][d]*V[t][e], likewise Ss.
// Sst slot layout: [blk*8192 + {0..4095: Sc, 4096..8191: Ss}], Zst: blk*128.
// ---------------------------------------------------------------------------
__global__ __launch_bounds__(256) void k_chunk_kv(
    const float* __restrict__ Kg, const float* __restrict__ Vg,
    float* __restrict__ Sst, float* __restrict__ Zst)
{
    __shared__ __align__(16) float Kb[C_ * 64];
    __shared__ __align__(16) float Vb[C_ * 64];
    __shared__ float cosA[C_], sinA[C_];

    const int blk = blockIdx.x;          // bh*G + g
    const int bh = blk >> 5, g = blk & 31;
    const int b = bh >> 3, h = bh & 7;
    const int tid = threadIdx.x;
    const int rBase = b * T_ + g * C_;
    const int colB = h * DK_;

    for (int v = tid; v < 512; v += 256) {   // 512 float4 per array
        int row = v >> 4, c4 = (v & 15) * 4;
        size_t ga = (size_t)(rBase + row) * D_ + colB + c4;
        *(float4*)&Kb[row * 64 + c4] = *(const float4*)&Kg[ga];
        *(float4*)&Vb[row * 64 + c4] = *(const float4*)&Vg[ga];
    }
    if (tid < C_) {
        float a = (float)(g * C_ + tid) * PI_OVER_2T;
        cosA[tid] = cosf(a); sinA[tid] = sinf(a);
    }
    __syncthreads();

    const int d = tid >> 2;              // 0..63
    const int e0 = (tid & 3) * 16;       // 0,16,32,48
    float sc[16], ss[16];
#pragma unroll
    for (int u = 0; u < 16; u++) { sc[u] = 0.f; ss[u] = 0.f; }
    float zc = 0.f, zs = 0.f;

    for (int t = 0; t < C_; t++) {
        float kk = Kb[t * 64 + d];
        float kc = kk * cosA[t], ks = kk * sinA[t];
        zc += kc; zs += ks;
#pragma unroll
        for (int u = 0; u < 4; u++) {
            float4 v4 = *(const float4*)&Vb[t * 64 + e0 + 4 * u];
            sc[4*u+0] += kc * v4.x; sc[4*u+1] += kc * v4.y;
            sc[4*u+2] += kc * v4.z; sc[4*u+3] += kc * v4.w;
            ss[4*u+0] += ks * v4.x; ss[4*u+1] += ks * v4.y;
            ss[4*u+2] += ks * v4.z; ss[4*u+3] += ks * v4.w;
        }
    }

    float* Sp = Sst + (size_t)blk * 8192;
#pragma unroll
    for (int u = 0; u < 4; u++) {
        *(float4*)&Sp[d * 64 + e0 + 4 * u] =
            make_float4(sc[4*u], sc[4*u+1], sc[4*u+2], sc[4*u+3]);
        *(float4*)&Sp[4096 + d * 64 + e0 + 4 * u] =
            make_float4(ss[4*u], ss[4*u+1], ss[4*u+2], ss[4*u+3]);
    }
    if ((tid & 3) == 0) {
        Zst[(size_t)blk * 128 + d] = zc;
        Zst[(size_t)blk * 128 + 64 + d] = zs;
    }
}

// ---------------------------------------------------------------------------
// Kernel 3: in-place exclusive scan over chunks g for each (bh, element).
// p[(bh*G+g)*E + i]  ->  sum over g' < g.
// ---------------------------------------------------------------------------
__global__ __launch_bounds__(256) void k_scan(float* __restrict__ p, int E)
{
    int id = blockIdx.x * 256 + threadIdx.x;
    int bh = id / E, i = id % E;
    if (bh >= NBH_) return;
    float run = 0.f;
    for (int g = 0; g < G_; g++) {
        size_t a = ((size_t)(bh * G_ + g)) * E + i;
        float t = p[a];
        p[a] = run;
        run += t;
    }
}

// ---------------------------------------------------------------------------
// Kernel 4: per-chunk output.
// o[t] = (P_masked @ V + Qc@Sc_pre + Qs@Ss_pre) / z * gate, P[t][s]=Q.K*cos(at-as)
// ---------------------------------------------------------------------------
__global__ __launch_bounds__(256) void k_out_chunk(
    const float* __restrict__ Qg, const float* __restrict__ Kg,
    const float* __restrict__ Vg, const float* __restrict__ Gg,
    const float* __restrict__ Sst, const float* __restrict__ Zst,
    float* __restrict__ Op)
{
    __shared__ __align__(16) float Qb[C_ * 68];    // [t][d] pad 68
    __shared__ __align__(16) float R1[64 * 36];    // ph1: KbT[d*36+t]; ph2+: Vb[s*68+e]
    __shared__ __align__(16) float Scb[64 * 68];   // [d][e] pad 68
    __shared__ __align__(16) float Ssb[64 * 68];
    __shared__ __align__(16) float Pb[C_ * 36];    // [t][s] pad 36
    __shared__ float cosA[C_], sinA[C_], zinv[C_], zcb[64], zsb[64];

    const int blk = blockIdx.x;          // bh*G + g
    const int bh = blk >> 5, g = blk & 31;
    const int b = bh >> 3, h = bh & 7;
    const int tid = threadIdx.x;
    const int rBase = b * T_ + g * C_;
    const int colB = h * DK_;

    // ---- phase 0: load Q, K^T, Sc/Ss prefix, z prefix, cos/sin
    for (int v = tid; v < 512; v += 256) {
        int row = v >> 4, c4 = (v & 15) * 4;
        size_t ga = (size_t)(rBase + row) * D_ + colB + c4;
        float4 q4 = *(const float4*)&Qg[ga];
        *(float4*)&Qb[row * 68 + c4] = q4;
        float4 k4 = *(const float4*)&Kg[ga];
        R1[(c4 + 0) * 36 + row] = k4.x;
        R1[(c4 + 1) * 36 + row] = k4.y;
        R1[(c4 + 2) * 36 + row] = k4.z;
        R1[(c4 + 3) * 36 + row] = k4.w;
    }
    const float* Sbase = Sst + (size_t)blk * 8192;
    for (int v = tid; v < 1024; v += 256) {
        int d = v >> 4, e4 = (v & 15) * 4;
        *(float4*)&Scb[d * 68 + e4] = *(const float4*)&Sbase[d * 64 + e4];
        *(float4*)&Ssb[d * 68 + e4] = *(const float4*)&Sbase[4096 + d * 64 + e4];
    }
    if (tid < 64) {
        zcb[tid] = Zst[(size_t)blk * 128 + tid];
    } else if (tid < 128) {
        zsb[tid - 64] = Zst[(size_t)blk * 128 + 64 + (tid - 64)];
    } else if (tid < 160) {
        int t = tid - 128;
        float a = (float)(g * C_ + t) * PI_OVER_2T;
        cosA[t] = cosf(a); sinA[t] = sinf(a);
    }
    __syncthreads();

    // ---- phase 1: P[t][s] = (Q[t].K[s]) * cos(a_t - a_s), causal-masked
    {
        const int t = tid >> 3;
        const int s4 = (tid & 7) * 4;
        float a0 = 0.f, a1 = 0.f, a2 = 0.f, a3 = 0.f;
#pragma unroll 8
        for (int k = 0; k < 64; k++) {
            float q = Qb[t * 68 + k];
            float4 kv = *(const float4*)&R1[k * 36 + s4];
            a0 += q * kv.x; a1 += q * kv.y; a2 += q * kv.z; a3 += q * kv.w;
        }
        float ctt = cosA[t], stt = sinA[t];
        float r[4] = {a0, a1, a2, a3};
        float pr[4];
#pragma unroll
        for (int u = 0; u < 4; u++) {
            int s = s4 + u;
            float w = (s <= t) ? (ctt * cosA[s] + stt * sinA[s]) : 0.f;
            pr[u] = r[u] * w;
        }
        *(float4*)&Pb[t * 36 + s4] = make_float4(pr[0], pr[1], pr[2], pr[3]);
    }
    __syncthreads();

    // ---- phase 2: V into R1 (K^T dead), z and 1/z
    for (int v = tid; v < 512; v += 256) {
        int row = v >> 4, c4 = (v & 15) * 4;
        *(float4*)&R1[row * 68 + c4] =
            *(const float4*)&Vg[(size_t)(rBase + row) * D_ + colB + c4];
    }
    if (tid < C_) {
        const int t = tid;
        float ctt = cosA[t], stt = sinA[t];
        float z = 0.f;
        for (int d = 0; d < 64; d++)
            z += Qb[t * 68 + d] * (ctt * zcb[d] + stt * zsb[d]);
        for (int s = 0; s < C_; s++)
            z += Pb[t * 36 + s];
        zinv[t] = 1.f / fmaxf(z, 1e-6f);
    }
    __syncthreads();

    // ---- phase 3: o[t][e] = inter + intra, scale by zinv and gate
    {
        const int t = tid >> 3;
        const int e0 = (tid & 7) * 8;
        float o[8];
#pragma unroll
        for (int u = 0; u < 8; u++) o[u] = 0.f;
        float ctt = cosA[t], stt = sinA[t];
#pragma unroll 4
        for (int d = 0; d < 64; d++) {
            float q = Qb[t * 68 + d];
            float qc = q * ctt, qs = q * stt;
            float4 sc0 = *(const float4*)&Scb[d * 68 + e0];
            float4 sc1 = *(const float4*)&Scb[d * 68 + e0 + 4];
            float4 ss0 = *(const float4*)&Ssb[d * 68 + e0];
            float4 ss1 = *(const float4*)&Ssb[d * 68 + e0 + 4];
            o[0] += qc * sc0.x + qs * ss0.x;
            o[1] += qc * sc0.y + qs * ss0.y;
            o[2] += qc * sc0.z + qs * ss0.z;
            o[3] += qc * sc0.w + qs * ss0.w;
            o[4] += qc * sc1.x + qs * ss1.x;
            o[5] += qc * sc1.y + qs * ss1.y;
            o[6] += qc * sc1.z + qs * ss1.z;
            o[7] += qc * sc1.w + qs * ss1.w;
        }
#pragma unroll 4
        for (int s = 0; s < C_; s++) {
            float p = Pb[t * 36 + s];
            float4 v0 = *(const float4*)&R1[s * 68 + e0];
            float4 v1 = *(const float4*)&R1[s * 68 + e0 + 4];
            o[0] += p * v0.x; o[1] += p * v0.y;
            o[2] += p * v0.z; o[3] += p * v0.w;
            o[4] += p * v1.x; o[5] += p * v1.y;
            o[6] += p * v1.z; o[7] += p * v1.w;
        }
        const float zi = zinv[t];
        size_t go = (size_t)(rBase + t) * D_ + colB + e0;
        float4 g0 = *(const float4*)&Gg[go];
        float4 g1 = *(const float4*)&Gg[go + 4];
        float4 r0 = make_float4(o[0] * zi * g0.x, o[1] * zi * g0.y,
                                o[2] * zi * g0.z, o[3] * zi * g0.w);
        float4 r1 = make_float4(o[4] * zi * g1.x, o[5] * zi * g1.y,
                                o[6] * zi * g1.z, o[7] * zi * g1.w);
        *(float4*)&Op[go] = r0;
        *(float4*)&Op[go + 4] = r1;
    }
}

// ---------------------------------------------------------------------------
// Kernel 5: output projection.  out = Opre (2048x512) @ Wo (512x512).
// Tile 64x64, 4x4 microtile, BK=16.  grid (8 col-tiles, 32 row-tiles).
// ---------------------------------------------------------------------------
__global__ __launch_bounds__(256) void k_outproj(
    const float* __restrict__ A, const float* __restrict__ W,
    float* __restrict__ Out)
{
    __shared__ __align__(16) float AsT[16][68];
    __shared__ __align__(16) float Bs[16][64];
    const int ct = blockIdx.x;   // 0..7
    const int rt = blockIdx.y;   // 0..31
    const int tid = threadIdx.x;
    const int ty = tid >> 4, tx = tid & 15;
    const int rBase = rt * 64, jBase = ct * 64;
    float acc[4][4];
#pragma unroll
    for (int i = 0; i < 4; i++)
#pragma unroll
        for (int j = 0; j < 4; j++) acc[i][j] = 0.f;
    const int ar = tid >> 2;
    const int ak4 = (tid & 3) * 4;
    const int bk = tid >> 4;
    const int bc4 = (tid & 15) * 4;
    for (int kb = 0; kb < 512; kb += 16) {
        __syncthreads();
        float4 av = *(const float4*)&A[(size_t)(rBase + ar) * 512 + kb + ak4];
        AsT[ak4 + 0][ar] = av.x; AsT[ak4 + 1][ar] = av.y;
        AsT[ak4 + 2][ar] = av.z; AsT[ak4 + 3][ar] = av.w;
        *(float4*)&Bs[bk][bc4] =
            *(const float4*)&W[(size_t)(kb + bk) * 512 + jBase + bc4];
        __syncthreads();
#pragma unroll
        for (int k = 0; k < 16; k++) {
            float a[4], b[4];
            *(float4*)&a[0] = *(const float4*)&AsT[k][ty * 4];
            *(float4*)&b[0] = *(const float4*)&Bs[k][tx * 4];
#pragma unroll
            for (int i = 0; i < 4; i++)
#pragma unroll
                for (int j = 0; j < 4; j++) acc[i][j] += a[i] * b[j];
        }
    }
#pragma unroll
    for (int i = 0; i < 4; i++)
        *(float4*)&Out[(size_t)(rBase + ty * 4 + i) * 512 + jBase + tx * 4] =
            make_float4(acc[i][0], acc[i][1], acc[i][2], acc[i][3]);
}

// ---------------------------------------------------------------------------
extern "C" void kernel_launch(void* const* d_in, const int* in_sizes, int n_in,
                              void* d_out, int out_size, void* d_ws, size_t ws_size,
                              hipStream_t stream)
{
    const float* x  = (const float*)d_in[0];
    const float* Wq = (const float*)d_in[1];
    const float* Wk = (const float*)d_in[2];
    const float* Wv = (const float*)d_in[3];
    const float* Wo = (const float*)d_in[4];
    const float* Wg = (const float*)d_in[5];
    const float* bg = (const float*)d_in[6];
    float* out = (float*)d_out;

    float* ws = (float*)d_ws;
    float* Qg   = ws;                  // 2048*512
    float* Kg   = Qg + 1048576;
    float* Vg   = Kg + 1048576;
    float* Gg   = Vg + 1048576;
    float* Opre = Gg + 1048576;
    float* Sst  = Opre + 1048576;      // NBH*G*8192 = 4194304
    float* Zst  = Sst + 4194304;       // NBH*G*128  = 65536

    dim3 blk(256);
    k_proj<<<dim3(16, 16), blk, 0, stream>>>(x, Wq, Wk, Wv, Wg, bg, Qg, Kg, Vg, Gg);
    k_chunk_kv<<<dim3(NBH_ * G_), blk, 0, stream>>>(Kg, Vg, Sst, Zst);
    k_scan<<<dim3(512), blk, 0, stream>>>(Sst, 8192);
    k_scan<<<dim3(8), blk, 0, stream>>>(Zst, 128);
    k_out_chunk<<<dim3(NBH_ * G_), blk, 0, stream>>>(Qg, Kg, Vg, Gg, Sst, Zst, Opre);
    k_outproj<<<dim3(8, 32), blk, 0, stream>>>(Opre, Wo, out);
}

// Round 2
// 156.689 us; speedup vs baseline: 1.3668x; 1.3668x over previous
//
#include <hip/hip_runtime.h>
#include <math.h>

// Problem constants
#define B_ 2
#define T_ 1024
#define D_ 512
#define H_ 8
#define DK_ 64
#define NBH_ 16          // B*H
#define C_ 32            // chunk length
#define G_ 32            // T/C chunks

#define PI_OVER_2T 0.00153398078788564122971808758949f  /* pi/2048 */

typedef float f32x4 __attribute__((ext_vector_type(4)));
typedef short s16x8 __attribute__((ext_vector_type(8)));

__device__ __forceinline__ ushort f2bf(float x) {
    unsigned u = __float_as_uint(x);
    unsigned r = (u + 0x7fffu + ((u >> 16) & 1u)) >> 16;   // RNE
    return (ushort)r;
}

// async global->LDS, 16B per lane. LDS dest = wave-uniform base + lane*16
// (m104), so per-lane lds ptr must be tid-contiguous in issue order.
__device__ __forceinline__ void async16(void* lds, const void* g) {
    __builtin_amdgcn_global_load_lds(
        (const __attribute__((address_space(1))) void*)g,
        (__attribute__((address_space(3))) void*)lds, 16, 0, 0);
}

// ---------------------------------------------------------------------------
// Convert x (2048x512 f32) -> bf16 row-major.
// ---------------------------------------------------------------------------
__global__ __launch_bounds__(256) void k_convx(
    const float* __restrict__ x, ushort* __restrict__ xb)
{
    int i = (blockIdx.x * 256 + threadIdx.x) * 4;
    float4 v = *(const float4*)&x[i];
    ushort4 o;
    o.x = f2bf(v.x); o.y = f2bf(v.y); o.z = f2bf(v.z); o.w = f2bf(v.w);
    *(ushort4*)&xb[i] = o;
}

// ---------------------------------------------------------------------------
// Convert+transpose 5 weight matrices (512x512 f32, (k,n)) -> WtAll bf16 (n,k).
// grid (64, 5); 64x64 tile per block.
// ---------------------------------------------------------------------------
__global__ __launch_bounds__(256) void k_convw(
    const float* __restrict__ Wq, const float* __restrict__ Wk,
    const float* __restrict__ Wv, const float* __restrict__ Wg,
    const float* __restrict__ Wo, ushort* __restrict__ WtAll)
{
    __shared__ float Ts[64][65];
    const int mi = blockIdx.y;
    const float* __restrict__ W = (mi == 0) ? Wq : (mi == 1) ? Wk
                                 : (mi == 2) ? Wv : (mi == 3) ? Wg : Wo;
    const int tr = blockIdx.x >> 3, tc = blockIdx.x & 7;
    const int tid = threadIdx.x;
#pragma unroll
    for (int p = 0; p < 4; p++) {
        int row = p * 16 + (tid >> 4);
        int c4 = (tid & 15) * 4;
        float4 v = *(const float4*)&W[(size_t)(tr * 64 + row) * 512 + tc * 64 + c4];
        Ts[row][c4 + 0] = v.x; Ts[row][c4 + 1] = v.y;
        Ts[row][c4 + 2] = v.z; Ts[row][c4 + 3] = v.w;
    }
    __syncthreads();
    const int nl = tid >> 2, kc = (tid & 3) * 16;
    ushort buf[16];
#pragma unroll
    for (int u = 0; u < 16; u++) buf[u] = f2bf(Ts[kc + u][nl]);
    ushort* dst = WtAll + (size_t)mi * 262144 + (size_t)(tc * 64 + nl) * 512
                  + tr * 64 + kc;
    *(uint4*)dst = *(uint4*)&buf[0];
    *(uint4*)(dst + 8) = *(uint4*)&buf[8];
}

// ---------------------------------------------------------------------------
// bf16 MFMA GEMM, m97 recipe: 128x128 tile, BK=32, 4 waves each 64x64.
// A (M,512) bf16 row-major; Bt (N,512) bf16 row-major (pre-transposed).
// LDS chunk-XOR swizzle: LDS[row][c] holds global chunk c ^ ((row>>1)&3)
// so frag ds_read_b128 is <=2-way bank-conflicted (free, m136).
// MODE 0: proj - blockIdx.x>>2 selects {Q,K,V,G} matrix + activation.
// MODE 1: out-projection, single fp32 output, N=512.
// ---------------------------------------------------------------------------
template<int MODE>
__global__ __launch_bounds__(256) void k_gemm(
    const ushort* __restrict__ A, const ushort* __restrict__ Bt,
    const float* __restrict__ bg,
    float* __restrict__ O0, float* __restrict__ O1,
    float* __restrict__ O2, float* __restrict__ O3)
{
    __shared__ ushort As[128 * 32];
    __shared__ ushort Bs[128 * 32];

    const int tid = threadIdx.x;
    const int ct = blockIdx.x;
    const int rowBase = blockIdx.y * 128;
    const ushort* __restrict__ Bmat;
    int nBaseG;
    if (MODE == 0) { Bmat = Bt + (size_t)(ct >> 2) * 262144; nBaseG = (ct & 3) * 128; }
    else           { Bmat = Bt;                               nBaseG = ct * 128; }

    const int wave = tid >> 6, lane = tid & 63;
    const int q = lane >> 4, ln = lane & 15;
    const int mB = (wave >> 1) * 64, nB = (wave & 1) * 64;

    // staging indices (ushort units): 2 issues of 16B per thread per tile
    int fu0 = tid * 8, fu1 = tid * 8 + 2048;
    int r0 = fu0 >> 5, r1 = fu1 >> 5;
    int g0 = (((fu0 >> 3) & 3) ^ ((r0 >> 1) & 3)) * 8;
    int g1 = (((fu1 >> 3) & 3) ^ ((r1 >> 1) & 3)) * 8;
    const ushort* gA0 = A + (size_t)(rowBase + r0) * 512 + g0;
    const ushort* gA1 = A + (size_t)(rowBase + r1) * 512 + g1;
    const ushort* gB0 = Bmat + (size_t)(nBaseG + r0) * 512 + g0;
    const ushort* gB1 = Bmat + (size_t)(nBaseG + r1) * 512 + g1;

    f32x4 acc[4][4];
#pragma unroll
    for (int i = 0; i < 4; i++)
#pragma unroll
        for (int j = 0; j < 4; j++) acc[i][j] = (f32x4){0.f, 0.f, 0.f, 0.f};

    // frag LDS offsets (constant across K-loop)
    int aoff[4], boff[4];
#pragma unroll
    for (int i = 0; i < 4; i++) {
        int ra = mB + i * 16 + ln;
        aoff[i] = ra * 32 + ((q ^ ((ra >> 1) & 3)) * 8);
        int rb = nB + i * 16 + ln;
        boff[i] = rb * 32 + ((q ^ ((rb >> 1) & 3)) * 8);
    }

    for (int kb = 0; kb < 512; kb += 32) {
        __syncthreads();
        async16(&As[fu0], gA0 + kb);
        async16(&As[fu1], gA1 + kb);
        async16(&Bs[fu0], gB0 + kb);
        async16(&Bs[fu1], gB1 + kb);
        __syncthreads();
        s16x8 af[4], bf[4];
#pragma unroll
        for (int i = 0; i < 4; i++) af[i] = *(const s16x8*)&As[aoff[i]];
#pragma unroll
        for (int j = 0; j < 4; j++) bf[j] = *(const s16x8*)&Bs[boff[j]];
#pragma unroll
        for (int i = 0; i < 4; i++)
#pragma unroll
            for (int j = 0; j < 4; j++)
                acc[i][j] = __builtin_amdgcn_mfma_f32_16x16x32_bf16(
                    af[i], bf[j], acc[i][j], 0, 0, 0);
    }

    // epilogue: C/D layout col=lane&15, row=quad*4+reg (m89-verified)
    if (MODE == 0) {
        const int which = ct >> 2;
        float* __restrict__ Out = (which == 0) ? O0 : (which == 1) ? O1
                                 : (which == 2) ? O2 : O3;
        const int matCol = (ct & 3) * 128;
#pragma unroll
        for (int i = 0; i < 4; i++)
#pragma unroll
            for (int j = 0; j < 4; j++) {
                int col = matCol + nB + j * 16 + ln;
#pragma unroll
                for (int r = 0; r < 4; r++) {
                    int row = rowBase + mB + i * 16 + q * 4 + r;
                    float v = acc[i][j][r];
                    if (which <= 1) v = fmaxf(v, 0.f);
                    else if (which == 3) v = 1.f / (1.f + expf(-(v + bg[col])));
                    Out[(size_t)row * 512 + col] = v;
                }
            }
    } else {
#pragma unroll
        for (int i = 0; i < 4; i++)
#pragma unroll
            for (int j = 0; j < 4; j++) {
                int col = ct * 128 + nB + j * 16 + ln;
#pragma unroll
                for (int r = 0; r < 4; r++) {
                    int row = rowBase + mB + i * 16 + q * 4 + r;
                    O0[(size_t)row * 512 + col] = acc[i][j][r];
                }
            }
    }
}

// ---------------------------------------------------------------------------
// Kernel: per-chunk KV outer-product local sums (fp32, unchanged).
// ---------------------------------------------------------------------------
__global__ __launch_bounds__(256) void k_chunk_kv(
    const float* __restrict__ Kg, const float* __restrict__ Vg,
    float* __restrict__ Sst, float* __restrict__ Zst)
{
    __shared__ __align__(16) float Kb[C_ * 64];
    __shared__ __align__(16) float Vb[C_ * 64];
    __shared__ float cosA[C_], sinA[C_];

    const int blk = blockIdx.x;
    const int bh = blk >> 5, g = blk & 31;
    const int b = bh >> 3, h = bh & 7;
    const int tid = threadIdx.x;
    const int rBase = b * T_ + g * C_;
    const int colB = h * DK_;

    for (int v = tid; v < 512; v += 256) {
        int row = v >> 4, c4 = (v & 15) * 4;
        size_t ga = (size_t)(rBase + row) * D_ + colB + c4;
        *(float4*)&Kb[row * 64 + c4] = *(const float4*)&Kg[ga];
        *(float4*)&Vb[row * 64 + c4] = *(const float4*)&Vg[ga];
    }
    if (tid < C_) {
        float a = (float)(g * C_ + tid) * PI_OVER_2T;
        cosA[tid] = cosf(a); sinA[tid] = sinf(a);
    }
    __syncthreads();

    const int d = tid >> 2;
    const int e0 = (tid & 3) * 16;
    float sc[16], ss[16];
#pragma unroll
    for (int u = 0; u < 16; u++) { sc[u] = 0.f; ss[u] = 0.f; }
    float zc = 0.f, zs = 0.f;

    for (int t = 0; t < C_; t++) {
        float kk = Kb[t * 64 + d];
        float kc = kk * cosA[t], ks = kk * sinA[t];
        zc += kc; zs += ks;
#pragma unroll
        for (int u = 0; u < 4; u++) {
            float4 v4 = *(const float4*)&Vb[t * 64 + e0 + 4 * u];
            sc[4*u+0] += kc * v4.x; sc[4*u+1] += kc * v4.y;
            sc[4*u+2] += kc * v4.z; sc[4*u+3] += kc * v4.w;
            ss[4*u+0] += ks * v4.x; ss[4*u+1] += ks * v4.y;
            ss[4*u+2] += ks * v4.z; ss[4*u+3] += ks * v4.w;
        }
    }

    float* Sp = Sst + (size_t)blk * 8192;
#pragma unroll
    for (int u = 0; u < 4; u++) {
        *(float4*)&Sp[d * 64 + e0 + 4 * u] =
            make_float4(sc[4*u], sc[4*u+1], sc[4*u+2], sc[4*u+3]);
        *(float4*)&Sp[4096 + d * 64 + e0 + 4 * u] =
            make_float4(ss[4*u], ss[4*u+1], ss[4*u+2], ss[4*u+3]);
    }
    if ((tid & 3) == 0) {
        Zst[(size_t)blk * 128 + d] = zc;
        Zst[(size_t)blk * 128 + 64 + d] = zs;
    }
}

// ---------------------------------------------------------------------------
// Exclusive scan over chunks, float4-vectorized.
// ---------------------------------------------------------------------------
__global__ __launch_bounds__(256) void k_scan(float* __restrict__ p, int E)
{
    int id = blockIdx.x * 256 + threadIdx.x;
    int E4 = E >> 2;
    if (id >= NBH_ * E4) return;
    int bh = id / E4, i4 = (id % E4) * 4;
    float4 run = make_float4(0.f, 0.f, 0.f, 0.f);
    for (int g = 0; g < G_; g++) {
        float4* a = (float4*)&p[(size_t)(bh * G_ + g) * E + i4];
        float4 t = *a;
        *a = run;
        run.x += t.x; run.y += t.y; run.z += t.z; run.w += t.w;
    }
}

// ---------------------------------------------------------------------------
// Per-chunk output (fp32 math), now writes bf16 Opre for the MFMA out-proj.
// ---------------------------------------------------------------------------
__global__ __launch_bounds__(256) void k_out_chunk(
    const float* __restrict__ Qg, const float* __restrict__ Kg,
    const float* __restrict__ Vg, const float* __restrict__ Gg,
    const float* __restrict__ Sst, const float* __restrict__ Zst,
    ushort* __restrict__ Op)
{
    __shared__ __align__(16) float Qb[C_ * 68];
    __shared__ __align__(16) float R1[64 * 68];
    __shared__ __align__(16) float Scb[64 * 68];
    __shared__ __align__(16) float Ssb[64 * 68];
    __shared__ __align__(16) float Pb[C_ * 36];
    __shared__ float cosA[C_], sinA[C_], zinv[C_], zcb[64], zsb[64];

    const int blk = blockIdx.x;
    const int bh = blk >> 5, g = blk & 31;
    const int b = bh >> 3, h = bh & 7;
    const int tid = threadIdx.x;
    const int rBase = b * T_ + g * C_;
    const int colB = h * DK_;

    // ---- phase 0
    for (int v = tid; v < 512; v += 256) {
        int row = v >> 4, c4 = (v & 15) * 4;
        size_t ga = (size_t)(rBase + row) * D_ + colB + c4;
        float4 q4 = *(const float4*)&Qg[ga];
        *(float4*)&Qb[row * 68 + c4] = q4;
        float4 k4 = *(const float4*)&Kg[ga];
        R1[(c4 + 0) * 36 + row] = k4.x;
        R1[(c4 + 1) * 36 + row] = k4.y;
        R1[(c4 + 2) * 36 + row] = k4.z;
        R1[(c4 + 3) * 36 + row] = k4.w;
    }
    const float* Sbase = Sst + (size_t)blk * 8192;
    for (int v = tid; v < 1024; v += 256) {
        int d = v >> 4, e4 = (v & 15) * 4;
        *(float4*)&Scb[d * 68 + e4] = *(const float4*)&Sbase[d * 64 + e4];
        *(float4*)&Ssb[d * 68 + e4] = *(const float4*)&Sbase[4096 + d * 64 + e4];
    }
    if (tid < 64) {
        zcb[tid] = Zst[(size_t)blk * 128 + tid];
    } else if (tid < 128) {
        zsb[tid - 64] = Zst[(size_t)blk * 128 + 64 + (tid - 64)];
    } else if (tid < 160) {
        int t = tid - 128;
        float a = (float)(g * C_ + t) * PI_OVER_2T;
        cosA[t] = cosf(a); sinA[t] = sinf(a);
    }
    __syncthreads();

    // ---- phase 1: P[t][s]
    {
        const int t = tid >> 3;
        const int s4 = (tid & 7) * 4;
        float a0 = 0.f, a1 = 0.f, a2 = 0.f, a3 = 0.f;
#pragma unroll 8
        for (int k = 0; k < 64; k++) {
            float qv = Qb[t * 68 + k];
            float4 kv = *(const float4*)&R1[k * 36 + s4];
            a0 += qv * kv.x; a1 += qv * kv.y; a2 += qv * kv.z; a3 += qv * kv.w;
        }
        float ctt = cosA[t], stt = sinA[t];
        float r[4] = {a0, a1, a2, a3};
        float pr[4];
#pragma unroll
        for (int u = 0; u < 4; u++) {
            int s = s4 + u;
            float w = (s <= t) ? (ctt * cosA[s] + stt * sinA[s]) : 0.f;
            pr[u] = r[u] * w;
        }
        *(float4*)&Pb[t * 36 + s4] = make_float4(pr[0], pr[1], pr[2], pr[3]);
    }
    __syncthreads();

    // ---- phase 2: V into R1, z
    for (int v = tid; v < 512; v += 256) {
        int row = v >> 4, c4 = (v & 15) * 4;
        *(float4*)&R1[row * 68 + c4] =
            *(const float4*)&Vg[(size_t)(rBase + row) * D_ + colB + c4];
    }
    if (tid < C_) {
        const int t = tid;
        float ctt = cosA[t], stt = sinA[t];
        float z = 0.f;
        for (int d = 0; d < 64; d++)
            z += Qb[t * 68 + d] * (ctt * zcb[d] + stt * zsb[d]);
        for (int s = 0; s < C_; s++)
            z += Pb[t * 36 + s];
        zinv[t] = 1.f / fmaxf(z, 1e-6f);
    }
    __syncthreads();

    // ---- phase 3
    {
        const int t = tid >> 3;
        const int e0 = (tid & 7) * 8;
        float o[8];
#pragma unroll
        for (int u = 0; u < 8; u++) o[u] = 0.f;
        float ctt = cosA[t], stt = sinA[t];
#pragma unroll 4
        for (int d = 0; d < 64; d++) {
            float qv = Qb[t * 68 + d];
            float qc = qv * ctt, qs = qv * stt;
            float4 sc0 = *(const float4*)&Scb[d * 68 + e0];
            float4 sc1 = *(const float4*)&Scb[d * 68 + e0 + 4];
            float4 ss0 = *(const float4*)&Ssb[d * 68 + e0];
            float4 ss1 = *(const float4*)&Ssb[d * 68 + e0 + 4];
            o[0] += qc * sc0.x + qs * ss0.x;
            o[1] += qc * sc0.y + qs * ss0.y;
            o[2] += qc * sc0.z + qs * ss0.z;
            o[3] += qc * sc0.w + qs * ss0.w;
            o[4] += qc * sc1.x + qs * ss1.x;
            o[5] += qc * sc1.y + qs * ss1.y;
            o[6] += qc * sc1.z + qs * ss1.z;
            o[7] += qc * sc1.w + qs * ss1.w;
        }
#pragma unroll 4
        for (int s = 0; s < C_; s++) {
            float p = Pb[t * 36 + s];
            float4 v0 = *(const float4*)&R1[s * 68 + e0];
            float4 v1 = *(const float4*)&R1[s * 68 + e0 + 4];
            o[0] += p * v0.x; o[1] += p * v0.y;
            o[2] += p * v0.z; o[3] += p * v0.w;
            o[4] += p * v1.x; o[5] += p * v1.y;
            o[6] += p * v1.z; o[7] += p * v1.w;
        }
        const float zi = zinv[t];
        size_t go = (size_t)(rBase + t) * D_ + colB + e0;
        float4 g0 = *(const float4*)&Gg[go];
        float4 g1 = *(const float4*)&Gg[go + 4];
        ushort r8[8];
        r8[0] = f2bf(o[0] * zi * g0.x); r8[1] = f2bf(o[1] * zi * g0.y);
        r8[2] = f2bf(o[2] * zi * g0.z); r8[3] = f2bf(o[3] * zi * g0.w);
        r8[4] = f2bf(o[4] * zi * g1.x); r8[5] = f2bf(o[5] * zi * g1.y);
        r8[6] = f2bf(o[6] * zi * g1.z); r8[7] = f2bf(o[7] * zi * g1.w);
        *(uint4*)&Op[go] = *(uint4*)r8;
    }
}

// ---------------------------------------------------------------------------
extern "C" void kernel_launch(void* const* d_in, const int* in_sizes, int n_in,
                              void* d_out, int out_size, void* d_ws, size_t ws_size,
                              hipStream_t stream)
{
    const float* x  = (const float*)d_in[0];
    const float* Wq = (const float*)d_in[1];
    const float* Wk = (const float*)d_in[2];
    const float* Wv = (const float*)d_in[3];
    const float* Wo = (const float*)d_in[4];
    const float* Wg = (const float*)d_in[5];
    const float* bg = (const float*)d_in[6];
    float* out = (float*)d_out;

    float* ws = (float*)d_ws;
    float* Qg   = ws;                   // 1M f32 each
    float* Kg   = Qg + 1048576;
    float* Vg   = Kg + 1048576;
    float* Gg   = Vg + 1048576;
    float* Sst  = Gg + 1048576;         // 4M f32
    float* Zst  = Sst + 4194304;        // 64K f32
    ushort* xb    = (ushort*)(Zst + 65536);   // 1M bf16
    ushort* WtAll = xb + 1048576;             // 5*256K bf16
    ushort* Opb   = WtAll + 1310720;          // 1M bf16

    dim3 blk(256);
    k_convx<<<dim3(1024), blk, 0, stream>>>(x, xb);
    k_convw<<<dim3(64, 5), blk, 0, stream>>>(Wq, Wk, Wv, Wg, Wo, WtAll);
    k_gemm<0><<<dim3(16, 16), blk, 0, stream>>>(xb, WtAll, bg, Qg, Kg, Vg, Gg);
    k_chunk_kv<<<dim3(NBH_ * G_), blk, 0, stream>>>(Kg, Vg, Sst, Zst);
    k_scan<<<dim3(128), blk, 0, stream>>>(Sst, 8192);
    k_scan<<<dim3(2), blk, 0, stream>>>(Zst, 128);
    k_out_chunk<<<dim3(NBH_ * G_), blk, 0, stream>>>(Qg, Kg, Vg, Gg, Sst, Zst, Opb);
    k_gemm<1><<<dim3(4, 16), blk, 0, stream>>>(
        Opb, WtAll + (size_t)4 * 262144, nullptr, out, nullptr, nullptr, nullptr);
}

// Round 3
// 134.718 us; speedup vs baseline: 1.5897x; 1.1631x over previous
//
#include <hip/hip_runtime.h>
#include <math.h>

// Problem constants
#define B_ 2
#define T_ 1024
#define D_ 512
#define H_ 8
#define DK_ 64
#define NBH_ 16          // B*H
#define C_ 32            // chunk length
#define G_ 32            // T/C chunks

#define PI_OVER_2T 0.00153398078788564122971808758949f  /* pi/2048 */

typedef float f32x4 __attribute__((ext_vector_type(4)));
typedef short s16x8 __attribute__((ext_vector_type(8)));

__device__ __forceinline__ ushort f2bf(float x) {
    unsigned u = __float_as_uint(x);
    unsigned r = (u + 0x7fffu + ((u >> 16) & 1u)) >> 16;   // RNE
    return (ushort)r;
}

// async global->LDS, 16B/lane; LDS dest must be tid-contiguous (m104).
__device__ __forceinline__ void async16(void* lds, const void* g) {
    __builtin_amdgcn_global_load_lds(
        (const __attribute__((address_space(1))) void*)g,
        (__attribute__((address_space(3))) void*)lds, 16, 0, 0);
}

// ---------------------------------------------------------------------------
// Fused convert kernel.
// blocks 0..1023: x (2048x512 f32) -> xb bf16.
// blocks 1024..1343: 5 weights (512x512 f32 (k,n)) -> WtAll bf16 (n,k).
// ---------------------------------------------------------------------------
__global__ __launch_bounds__(256) void k_conv(
    const float* __restrict__ x,
    const float* __restrict__ Wq, const float* __restrict__ Wk,
    const float* __restrict__ Wv, const float* __restrict__ Wg,
    const float* __restrict__ Wo,
    ushort* __restrict__ xb, ushort* __restrict__ WtAll)
{
    __shared__ float Ts[64][65];
    const int bx = blockIdx.x;
    const int tid = threadIdx.x;
    if (bx < 1024) {
        int i = (bx * 256 + tid) * 4;
        float4 v = *(const float4*)&x[i];
        ushort4 o;
        o.x = f2bf(v.x); o.y = f2bf(v.y); o.z = f2bf(v.z); o.w = f2bf(v.w);
        *(ushort4*)&xb[i] = o;
        return;
    }
    const int bid = bx - 1024;
    const int mi = bid >> 6;               // matrix index 0..4
    const int t64 = bid & 63;
    const float* __restrict__ W = (mi == 0) ? Wq : (mi == 1) ? Wk
                                 : (mi == 2) ? Wv : (mi == 3) ? Wg : Wo;
    const int tr = t64 >> 3, tc = t64 & 7;
#pragma unroll
    for (int p = 0; p < 4; p++) {
        int row = p * 16 + (tid >> 4);
        int c4 = (tid & 15) * 4;
        float4 v = *(const float4*)&W[(size_t)(tr * 64 + row) * 512 + tc * 64 + c4];
        Ts[row][c4 + 0] = v.x; Ts[row][c4 + 1] = v.y;
        Ts[row][c4 + 2] = v.z; Ts[row][c4 + 3] = v.w;
    }
    __syncthreads();
    const int nl = tid >> 2, kc = (tid & 3) * 16;
    ushort buf[16];
#pragma unroll
    for (int u = 0; u < 16; u++) buf[u] = f2bf(Ts[kc + u][nl]);
    ushort* dst = WtAll + (size_t)mi * 262144 + (size_t)(tc * 64 + nl) * 512
                  + tr * 64 + kc;
    *(uint4*)dst = *(uint4*)&buf[0];
    *(uint4*)(dst + 8) = *(uint4*)&buf[8];
}

// ---------------------------------------------------------------------------
// bf16 MFMA GEMM, double-buffered K-loop (single barrier per K-iter; the
// compiler's vmcnt(0)-before-s_barrier drain makes buf[cur] ready there).
// A (M,512) bf16 row-major; Bt (N,512) bf16 row-major (pre-transposed).
// Tile TM x TN, 4 waves each (TM/2)x(TN/2). XOR chunk swizzle keeps frag
// ds_read_b128 at <=2-way conflicts (free, m136).
// MODE 0: proj, N=4*512, selects {Q,K,V,G} + activation. MODE 1: out proj.
// ---------------------------------------------------------------------------
template<int MODE, int TM, int TN>
__global__ __launch_bounds__(256) void k_gemm(
    const ushort* __restrict__ A, const ushort* __restrict__ Bt,
    const float* __restrict__ bg,
    float* __restrict__ O0, float* __restrict__ O1,
    float* __restrict__ O2, float* __restrict__ O3)
{
    constexpr int WM = TM / 2, WN = TN / 2;
    constexpr int FM = WM / 16, FN = WN / 16;
    constexpr int NA = (TM * 32) / 2048;   // async16 issues per thread (A)
    constexpr int NB = (TN * 32) / 2048;

    __shared__ ushort As[2][TM * 32];
    __shared__ ushort Bs[2][TN * 32];

    const int tid = threadIdx.x;
    const int ct = blockIdx.x;
    const int rowBase = blockIdx.y * TM;

    const ushort* __restrict__ Bmat;
    int which = 0, matCol;
    if (MODE == 0) {
        which = ct / (512 / TN);
        matCol = (ct % (512 / TN)) * TN;
        Bmat = Bt + (size_t)which * 262144;
    } else {
        matCol = ct * TN;
        Bmat = Bt;
    }

    const int wave = tid >> 6, lane = tid & 63;
    const int q = lane >> 4, ln = lane & 15;
    const int mB = (wave >> 1) * WM, nB = (wave & 1) * WN;

    int fuA[NA], fuB[NB];
    const ushort* gA[NA];
    const ushort* gB[NB];
#pragma unroll
    for (int u = 0; u < NA; u++) {
        int fu = tid * 8 + u * 2048;
        int r = fu >> 5;
        int c = ((((fu >> 3) & 3) ^ ((r >> 1) & 3))) * 8;
        fuA[u] = fu;
        gA[u] = A + (size_t)(rowBase + r) * 512 + c;
    }
#pragma unroll
    for (int u = 0; u < NB; u++) {
        int fu = tid * 8 + u * 2048;
        int r = fu >> 5;
        int c = ((((fu >> 3) & 3) ^ ((r >> 1) & 3))) * 8;
        fuB[u] = fu;
        gB[u] = Bmat + (size_t)(matCol + r) * 512 + c;
    }

    f32x4 acc[FM][FN];
#pragma unroll
    for (int i = 0; i < FM; i++)
#pragma unroll
        for (int j = 0; j < FN; j++) acc[i][j] = (f32x4){0.f, 0.f, 0.f, 0.f};

    int aoff[FM], boff[FN];
#pragma unroll
    for (int i = 0; i < FM; i++) {
        int ra = mB + i * 16 + ln;
        aoff[i] = ra * 32 + ((q ^ ((ra >> 1) & 3)) * 8);
    }
#pragma unroll
    for (int j = 0; j < FN; j++) {
        int rb = nB + j * 16 + ln;
        boff[j] = rb * 32 + ((q ^ ((rb >> 1) & 3)) * 8);
    }

    // prologue: prefetch tile 0 into buffer 0
#pragma unroll
    for (int u = 0; u < NA; u++) async16(&As[0][fuA[u]], gA[u]);
#pragma unroll
    for (int u = 0; u < NB; u++) async16(&Bs[0][fuB[u]], gB[u]);

    int cur = 0;
    for (int kb = 0; kb < 512; kb += 32) {
        __syncthreads();                    // drains vmcnt -> buf[cur] ready
        if (kb + 32 < 512) {                // prefetch next tile into buf^1
#pragma unroll
            for (int u = 0; u < NA; u++)
                async16(&As[cur ^ 1][fuA[u]], gA[u] + kb + 32);
#pragma unroll
            for (int u = 0; u < NB; u++)
                async16(&Bs[cur ^ 1][fuB[u]], gB[u] + kb + 32);
        }
        s16x8 af[FM], bf[FN];
#pragma unroll
        for (int i = 0; i < FM; i++) af[i] = *(const s16x8*)&As[cur][aoff[i]];
#pragma unroll
        for (int j = 0; j < FN; j++) bf[j] = *(const s16x8*)&Bs[cur][boff[j]];
#pragma unroll
        for (int i = 0; i < FM; i++)
#pragma unroll
            for (int j = 0; j < FN; j++)
                acc[i][j] = __builtin_amdgcn_mfma_f32_16x16x32_bf16(
                    af[i], bf[j], acc[i][j], 0, 0, 0);
        cur ^= 1;
    }

    // epilogue: C/D layout col=lane&15, row=quad*4+reg (m89-verified)
    if (MODE == 0) {
        float* __restrict__ Out = (which == 0) ? O0 : (which == 1) ? O1
                                 : (which == 2) ? O2 : O3;
#pragma unroll
        for (int i = 0; i < FM; i++)
#pragma unroll
            for (int j = 0; j < FN; j++) {
                int col = matCol + nB + j * 16 + ln;
#pragma unroll
                for (int r = 0; r < 4; r++) {
                    int row = rowBase + mB + i * 16 + q * 4 + r;
                    float v = acc[i][j][r];
                    if (which <= 1) v = fmaxf(v, 0.f);
                    else if (which == 3) v = 1.f / (1.f + expf(-(v + bg[col])));
                    Out[(size_t)row * 512 + col] = v;
                }
            }
    } else {
#pragma unroll
        for (int i = 0; i < FM; i++)
#pragma unroll
            for (int j = 0; j < FN; j++) {
                int col = matCol + nB + j * 16 + ln;
#pragma unroll
                for (int r = 0; r < 4; r++) {
                    int row = rowBase + mB + i * 16 + q * 4 + r;
                    O0[(size_t)row * 512 + col] = acc[i][j][r];
                }
            }
    }
}

// ---------------------------------------------------------------------------
// Per-chunk KV outer-product local sums.
// ---------------------------------------------------------------------------
__global__ __launch_bounds__(256) void k_chunk_kv(
    const float* __restrict__ Kg, const float* __restrict__ Vg,
    float* __restrict__ Sst, float* __restrict__ Zst)
{
    __shared__ __align__(16) float Kb[C_ * 64];
    __shared__ __align__(16) float Vb[C_ * 64];
    __shared__ float cosA[C_], sinA[C_];

    const int blk = blockIdx.x;
    const int bh = blk >> 5, g = blk & 31;
    const int b = bh >> 3, h = bh & 7;
    const int tid = threadIdx.x;
    const int rBase = b * T_ + g * C_;
    const int colB = h * DK_;

    for (int v = tid; v < 512; v += 256) {
        int row = v >> 4, c4 = (v & 15) * 4;
        size_t ga = (size_t)(rBase + row) * D_ + colB + c4;
        *(float4*)&Kb[row * 64 + c4] = *(const float4*)&Kg[ga];
        *(float4*)&Vb[row * 64 + c4] = *(const float4*)&Vg[ga];
    }
    if (tid < C_) {
        float a = (float)(g * C_ + tid) * PI_OVER_2T;
        cosA[tid] = cosf(a); sinA[tid] = sinf(a);
    }
    __syncthreads();

    const int d = tid >> 2;
    const int e0 = (tid & 3) * 16;
    float sc[16], ss[16];
#pragma unroll
    for (int u = 0; u < 16; u++) { sc[u] = 0.f; ss[u] = 0.f; }
    float zc = 0.f, zs = 0.f;

    for (int t = 0; t < C_; t++) {
        float kk = Kb[t * 64 + d];
        float kc = kk * cosA[t], ks = kk * sinA[t];
        zc += kc; zs += ks;
#pragma unroll
        for (int u = 0; u < 4; u++) {
            float4 v4 = *(const float4*)&Vb[t * 64 + e0 + 4 * u];
            sc[4*u+0] += kc * v4.x; sc[4*u+1] += kc * v4.y;
            sc[4*u+2] += kc * v4.z; sc[4*u+3] += kc * v4.w;
            ss[4*u+0] += ks * v4.x; ss[4*u+1] += ks * v4.y;
            ss[4*u+2] += ks * v4.z; ss[4*u+3] += ks * v4.w;
        }
    }

    float* Sp = Sst + (size_t)blk * 8192;
#pragma unroll
    for (int u = 0; u < 4; u++) {
        *(float4*)&Sp[d * 64 + e0 + 4 * u] =
            make_float4(sc[4*u], sc[4*u+1], sc[4*u+2], sc[4*u+3]);
        *(float4*)&Sp[4096 + d * 64 + e0 + 4 * u] =
            make_float4(ss[4*u], ss[4*u+1], ss[4*u+2], ss[4*u+3]);
    }
    if ((tid & 3) == 0) {
        Zst[(size_t)blk * 128 + d] = zc;
        Zst[(size_t)blk * 128 + 64 + d] = zs;
    }
}

// ---------------------------------------------------------------------------
// Fused exclusive chunk-scan: Sst (first 32768 lanes) + Zst (next 512).
// grid = 130 blocks.
// ---------------------------------------------------------------------------
__global__ __launch_bounds__(256) void k_scan(
    float* __restrict__ Sst, float* __restrict__ Zst)
{
    int id = blockIdx.x * 256 + threadIdx.x;
    float* p; int E, i4, bh;
    if (id < 32768) {
        p = Sst; E = 8192; bh = id >> 11; i4 = (id & 2047) * 4;
    } else {
        int id2 = id - 32768;
        if (id2 >= 512) return;
        p = Zst; E = 128; bh = id2 >> 5; i4 = (id2 & 31) * 4;
    }
    float4 run = make_float4(0.f, 0.f, 0.f, 0.f);
    for (int g = 0; g < G_; g++) {
        float4* a = (float4*)&p[(size_t)(bh * G_ + g) * E + i4];
        float4 t = *a;
        *a = run;
        run.x += t.x; run.y += t.y; run.z += t.z; run.w += t.w;
    }
}

// ---------------------------------------------------------------------------
// Per-chunk output (fp32 math), writes bf16 Opre for the MFMA out-proj.
// ---------------------------------------------------------------------------
__global__ __launch_bounds__(256) void k_out_chunk(
    const float* __restrict__ Qg, const float* __restrict__ Kg,
    const float* __restrict__ Vg, const float* __restrict__ Gg,
    const float* __restrict__ Sst, const float* __restrict__ Zst,
    ushort* __restrict__ Op)
{
    __shared__ __align__(16) float Qb[C_ * 68];
    __shared__ __align__(16) float R1[64 * 68];
    __shared__ __align__(16) float Scb[64 * 68];
    __shared__ __align__(16) float Ssb[64 * 68];
    __shared__ __align__(16) float Pb[C_ * 36];
    __shared__ float cosA[C_], sinA[C_], zinv[C_], zcb[64], zsb[64];

    const int blk = blockIdx.x;
    const int bh = blk >> 5, g = blk & 31;
    const int b = bh >> 3, h = bh & 7;
    const int tid = threadIdx.x;
    const int rBase = b * T_ + g * C_;
    const int colB = h * DK_;

    // ---- phase 0
    for (int v = tid; v < 512; v += 256) {
        int row = v >> 4, c4 = (v & 15) * 4;
        size_t ga = (size_t)(rBase + row) * D_ + colB + c4;
        float4 q4 = *(const float4*)&Qg[ga];
        *(float4*)&Qb[row * 68 + c4] = q4;
        float4 k4 = *(const float4*)&Kg[ga];
        R1[(c4 + 0) * 36 + row] = k4.x;
        R1[(c4 + 1) * 36 + row] = k4.y;
        R1[(c4 + 2) * 36 + row] = k4.z;
        R1[(c4 + 3) * 36 + row] = k4.w;
    }
    const float* Sbase = Sst + (size_t)blk * 8192;
    for (int v = tid; v < 1024; v += 256) {
        int d = v >> 4, e4 = (v & 15) * 4;
        *(float4*)&Scb[d * 68 + e4] = *(const float4*)&Sbase[d * 64 + e4];
        *(float4*)&Ssb[d * 68 + e4] = *(const float4*)&Sbase[4096 + d * 64 + e4];
    }
    if (tid < 64) {
        zcb[tid] = Zst[(size_t)blk * 128 + tid];
    } else if (tid < 128) {
        zsb[tid - 64] = Zst[(size_t)blk * 128 + 64 + (tid - 64)];
    } else if (tid < 160) {
        int t = tid - 128;
        float a = (float)(g * C_ + t) * PI_OVER_2T;
        cosA[t] = cosf(a); sinA[t] = sinf(a);
    }
    __syncthreads();

    // ---- phase 1: P[t][s]
    {
        const int t = tid >> 3;
        const int s4 = (tid & 7) * 4;
        float a0 = 0.f, a1 = 0.f, a2 = 0.f, a3 = 0.f;
#pragma unroll 8
        for (int k = 0; k < 64; k++) {
            float qv = Qb[t * 68 + k];
            float4 kv = *(const float4*)&R1[k * 36 + s4];
            a0 += qv * kv.x; a1 += qv * kv.y; a2 += qv * kv.z; a3 += qv * kv.w;
        }
        float ctt = cosA[t], stt = sinA[t];
        float r[4] = {a0, a1, a2, a3};
        float pr[4];
#pragma unroll
        for (int u = 0; u < 4; u++) {
            int s = s4 + u;
            float w = (s <= t) ? (ctt * cosA[s] + stt * sinA[s]) : 0.f;
            pr[u] = r[u] * w;
        }
        *(float4*)&Pb[t * 36 + s4] = make_float4(pr[0], pr[1], pr[2], pr[3]);
    }
    __syncthreads();

    // ---- phase 2: V into R1, z
    for (int v = tid; v < 512; v += 256) {
        int row = v >> 4, c4 = (v & 15) * 4;
        *(float4*)&R1[row * 68 + c4] =
            *(const float4*)&Vg[(size_t)(rBase + row) * D_ + colB + c4];
    }
    if (tid < C_) {
        const int t = tid;
        float ctt = cosA[t], stt = sinA[t];
        float z = 0.f;
        for (int d = 0; d < 64; d++)
            z += Qb[t * 68 + d] * (ctt * zcb[d] + stt * zsb[d]);
        for (int s = 0; s < C_; s++)
            z += Pb[t * 36 + s];
        zinv[t] = 1.f / fmaxf(z, 1e-6f);
    }
    __syncthreads();

    // ---- phase 3
    {
        const int t = tid >> 3;
        const int e0 = (tid & 7) * 8;
        float o[8];
#pragma unroll
        for (int u = 0; u < 8; u++) o[u] = 0.f;
        float ctt = cosA[t], stt = sinA[t];
#pragma unroll 4
        for (int d = 0; d < 64; d++) {
            float qv = Qb[t * 68 + d];
            float qc = qv * ctt, qs = qv * stt;
            float4 sc0 = *(const float4*)&Scb[d * 68 + e0];
            float4 sc1 = *(const float4*)&Scb[d * 68 + e0 + 4];
            float4 ss0 = *(const float4*)&Ssb[d * 68 + e0];
            float4 ss1 = *(const float4*)&Ssb[d * 68 + e0 + 4];
            o[0] += qc * sc0.x + qs * ss0.x;
            o[1] += qc * sc0.y + qs * ss0.y;
            o[2] += qc * sc0.z + qs * ss0.z;
            o[3] += qc * sc0.w + qs * ss0.w;
            o[4] += qc * sc1.x + qs * ss1.x;
            o[5] += qc * sc1.y + qs * ss1.y;
            o[6] += qc * sc1.z + qs * ss1.z;
            o[7] += qc * sc1.w + qs * ss1.w;
        }
#pragma unroll 4
        for (int s = 0; s < C_; s++) {
            float p = Pb[t * 36 + s];
            float4 v0 = *(const float4*)&R1[s * 68 + e0];
            float4 v1 = *(const float4*)&R1[s * 68 + e0 + 4];
            o[0] += p * v0.x; o[1] += p * v0.y;
            o[2] += p * v0.z; o[3] += p * v0.w;
            o[4] += p * v1.x; o[5] += p * v1.y;
            o[6] += p * v1.z; o[7] += p * v1.w;
        }
        const float zi = zinv[t];
        size_t go = (size_t)(rBase + t) * D_ + colB + e0;
        float4 g0 = *(const float4*)&Gg[go];
        float4 g1 = *(const float4*)&Gg[go + 4];
        ushort r8[8];
        r8[0] = f2bf(o[0] * zi * g0.x); r8[1] = f2bf(o[1] * zi * g0.y);
        r8[2] = f2bf(o[2] * zi * g0.z); r8[3] = f2bf(o[3] * zi * g0.w);
        r8[4] = f2bf(o[4] * zi * g1.x); r8[5] = f2bf(o[5] * zi * g1.y);
        r8[6] = f2bf(o[6] * zi * g1.z); r8[7] = f2bf(o[7] * zi * g1.w);
        *(uint4*)&Op[go] = *(uint4*)r8;
    }
}

// ---------------------------------------------------------------------------
extern "C" void kernel_launch(void* const* d_in, const int* in_sizes, int n_in,
                              void* d_out, int out_size, void* d_ws, size_t ws_size,
                              hipStream_t stream)
{
    const float* x  = (const float*)d_in[0];
    const float* Wq = (const float*)d_in[1];
    const float* Wk = (const float*)d_in[2];
    const float* Wv = (const float*)d_in[3];
    const float* Wo = (const float*)d_in[4];
    const float* Wg = (const float*)d_in[5];
    const float* bg = (const float*)d_in[6];
    float* out = (float*)d_out;

    float* ws = (float*)d_ws;
    float* Qg   = ws;                   // 1M f32 each
    float* Kg   = Qg + 1048576;
    float* Vg   = Kg + 1048576;
    float* Gg   = Vg + 1048576;
    float* Sst  = Gg + 1048576;         // 4M f32
    float* Zst  = Sst + 4194304;        // 64K f32
    ushort* xb    = (ushort*)(Zst + 65536);   // 1M bf16
    ushort* WtAll = xb + 1048576;             // 5*256K bf16
    ushort* Opb   = WtAll + 1310720;          // 1M bf16

    dim3 blk(256);
    k_conv<<<dim3(1344), blk, 0, stream>>>(x, Wq, Wk, Wv, Wg, Wo, xb, WtAll);
    k_gemm<0, 128, 64><<<dim3(32, 16), blk, 0, stream>>>(
        xb, WtAll, bg, Qg, Kg, Vg, Gg);
    k_chunk_kv<<<dim3(NBH_ * G_), blk, 0, stream>>>(Kg, Vg, Sst, Zst);
    k_scan<<<dim3(130), blk, 0, stream>>>(Sst, Zst);
    k_out_chunk<<<dim3(NBH_ * G_), blk, 0, stream>>>(Qg, Kg, Vg, Gg, Sst, Zst, Opb);
    k_gemm<1, 64, 64><<<dim3(8, 32), blk, 0, stream>>>(
        Opb, WtAll + (size_t)4 * 262144, nullptr, out, nullptr, nullptr, nullptr);
}

// Round 4
// 126.828 us; speedup vs baseline: 1.6886x; 1.0622x over previous
//
#include <hip/hip_runtime.h>
#include <math.h>

// Problem constants
#define B_ 2
#define T_ 1024
#define D_ 512
#define H_ 8
#define DK_ 64
#define NBH_ 16          // B*H
#define C_ 32            // chunk length
#define G_ 32            // T/C chunks

#define PI_OVER_2T 0.00153398078788564122971808758949f  /* pi/2048 */

typedef float f32x4 __attribute__((ext_vector_type(4)));
typedef short s16x8 __attribute__((ext_vector_type(8)));

__device__ __forceinline__ ushort f2bf(float x) {
    unsigned u = __float_as_uint(x);
    unsigned r = (u + 0x7fffu + ((u >> 16) & 1u)) >> 16;   // RNE
    return (ushort)r;
}
__device__ __forceinline__ float bf2f(ushort u) {
    return __uint_as_float((unsigned)u << 16);
}

// async global->LDS, 16B/lane; LDS dest must be tid-contiguous (m104).
__device__ __forceinline__ void async16(void* lds, const void* g) {
    __builtin_amdgcn_global_load_lds(
        (const __attribute__((address_space(1))) void*)g,
        (__attribute__((address_space(3))) void*)lds, 16, 0, 0);
}

// ---------------------------------------------------------------------------
// Fused convert kernel.
// blocks 0..1023: x (2048x512 f32) -> xb bf16.
// blocks 1024..1343: 5 weights (512x512 f32 (k,n)) -> WtAll bf16 (n,k).
// ---------------------------------------------------------------------------
__global__ __launch_bounds__(256) void k_conv(
    const float* __restrict__ x,
    const float* __restrict__ Wq, const float* __restrict__ Wk,
    const float* __restrict__ Wv, const float* __restrict__ Wg,
    const float* __restrict__ Wo,
    ushort* __restrict__ xb, ushort* __restrict__ WtAll)
{
    __shared__ float Ts[64][65];
    const int bx = blockIdx.x;
    const int tid = threadIdx.x;
    if (bx < 1024) {
        int i = (bx * 256 + tid) * 4;
        float4 v = *(const float4*)&x[i];
        ushort4 o;
        o.x = f2bf(v.x); o.y = f2bf(v.y); o.z = f2bf(v.z); o.w = f2bf(v.w);
        *(ushort4*)&xb[i] = o;
        return;
    }
    const int bid = bx - 1024;
    const int mi = bid >> 6;               // matrix index 0..4
    const int t64 = bid & 63;
    const float* __restrict__ W = (mi == 0) ? Wq : (mi == 1) ? Wk
                                 : (mi == 2) ? Wv : (mi == 3) ? Wg : Wo;
    const int tr = t64 >> 3, tc = t64 & 7;
#pragma unroll
    for (int p = 0; p < 4; p++) {
        int row = p * 16 + (tid >> 4);
        int c4 = (tid & 15) * 4;
        float4 v = *(const float4*)&W[(size_t)(tr * 64 + row) * 512 + tc * 64 + c4];
        Ts[row][c4 + 0] = v.x; Ts[row][c4 + 1] = v.y;
        Ts[row][c4 + 2] = v.z; Ts[row][c4 + 3] = v.w;
    }
    __syncthreads();
    const int nl = tid >> 2, kc = (tid & 3) * 16;
    ushort buf[16];
#pragma unroll
    for (int u = 0; u < 16; u++) buf[u] = f2bf(Ts[kc + u][nl]);
    ushort* dst = WtAll + (size_t)mi * 262144 + (size_t)(tc * 64 + nl) * 512
                  + tr * 64 + kc;
    *(uint4*)dst = *(uint4*)&buf[0];
    *(uint4*)(dst + 8) = *(uint4*)&buf[8];
}

// ---------------------------------------------------------------------------
// bf16 MFMA GEMM, double-buffered K-loop.
// A (M,512) bf16 rm; Bt (N,512) bf16 rm (pre-transposed). XOR chunk swizzle.
// MODE 0: proj -> bf16 outputs {Q,K,V,G} + activation.  MODE 1: f32 out.
// ---------------------------------------------------------------------------
template<int MODE, int TM, int TN>
__global__ __launch_bounds__(256) void k_gemm(
    const ushort* __restrict__ A, const ushort* __restrict__ Bt,
    const float* __restrict__ bg,
    void* __restrict__ O0v, void* __restrict__ O1v,
    void* __restrict__ O2v, void* __restrict__ O3v)
{
    constexpr int WM = TM / 2, WN = TN / 2;
    constexpr int FM = WM / 16, FN = WN / 16;
    constexpr int NA = (TM * 32) / 2048;
    constexpr int NB = (TN * 32) / 2048;

    __shared__ ushort As[2][TM * 32];
    __shared__ ushort Bs[2][TN * 32];

    const int tid = threadIdx.x;
    const int ct = blockIdx.x;
    const int rowBase = blockIdx.y * TM;

    const ushort* __restrict__ Bmat;
    int which = 0, matCol;
    if (MODE == 0) {
        which = ct / (512 / TN);
        matCol = (ct % (512 / TN)) * TN;
        Bmat = Bt + (size_t)which * 262144;
    } else {
        matCol = ct * TN;
        Bmat = Bt;
    }

    const int wave = tid >> 6, lane = tid & 63;
    const int q = lane >> 4, ln = lane & 15;
    const int mB = (wave >> 1) * WM, nB = (wave & 1) * WN;

    int fuA[NA], fuB[NB];
    const ushort* gA[NA];
    const ushort* gB[NB];
#pragma unroll
    for (int u = 0; u < NA; u++) {
        int fu = tid * 8 + u * 2048;
        int r = fu >> 5;
        int c = ((((fu >> 3) & 3) ^ ((r >> 1) & 3))) * 8;
        fuA[u] = fu;
        gA[u] = A + (size_t)(rowBase + r) * 512 + c;
    }
#pragma unroll
    for (int u = 0; u < NB; u++) {
        int fu = tid * 8 + u * 2048;
        int r = fu >> 5;
        int c = ((((fu >> 3) & 3) ^ ((r >> 1) & 3))) * 8;
        fuB[u] = fu;
        gB[u] = Bmat + (size_t)(matCol + r) * 512 + c;
    }

    f32x4 acc[FM][FN];
#pragma unroll
    for (int i = 0; i < FM; i++)
#pragma unroll
        for (int j = 0; j < FN; j++) acc[i][j] = (f32x4){0.f, 0.f, 0.f, 0.f};

    int aoff[FM], boff[FN];
#pragma unroll
    for (int i = 0; i < FM; i++) {
        int ra = mB + i * 16 + ln;
        aoff[i] = ra * 32 + ((q ^ ((ra >> 1) & 3)) * 8);
    }
#pragma unroll
    for (int j = 0; j < FN; j++) {
        int rb = nB + j * 16 + ln;
        boff[j] = rb * 32 + ((q ^ ((rb >> 1) & 3)) * 8);
    }

#pragma unroll
    for (int u = 0; u < NA; u++) async16(&As[0][fuA[u]], gA[u]);
#pragma unroll
    for (int u = 0; u < NB; u++) async16(&Bs[0][fuB[u]], gB[u]);

    int cur = 0;
    for (int kb = 0; kb < 512; kb += 32) {
        __syncthreads();
        if (kb + 32 < 512) {
#pragma unroll
            for (int u = 0; u < NA; u++)
                async16(&As[cur ^ 1][fuA[u]], gA[u] + kb + 32);
#pragma unroll
            for (int u = 0; u < NB; u++)
                async16(&Bs[cur ^ 1][fuB[u]], gB[u] + kb + 32);
        }
        s16x8 af[FM], bf[FN];
#pragma unroll
        for (int i = 0; i < FM; i++) af[i] = *(const s16x8*)&As[cur][aoff[i]];
#pragma unroll
        for (int j = 0; j < FN; j++) bf[j] = *(const s16x8*)&Bs[cur][boff[j]];
#pragma unroll
        for (int i = 0; i < FM; i++)
#pragma unroll
            for (int j = 0; j < FN; j++)
                acc[i][j] = __builtin_amdgcn_mfma_f32_16x16x32_bf16(
                    af[i], bf[j], acc[i][j], 0, 0, 0);
        cur ^= 1;
    }

    // epilogue: C/D layout col=lane&15, row=quad*4+reg (m89-verified)
    if (MODE == 0) {
        ushort* __restrict__ Out = (which == 0) ? (ushort*)O0v
                                  : (which == 1) ? (ushort*)O1v
                                  : (which == 2) ? (ushort*)O2v : (ushort*)O3v;
#pragma unroll
        for (int i = 0; i < FM; i++)
#pragma unroll
            for (int j = 0; j < FN; j++) {
                int col = matCol + nB + j * 16 + ln;
#pragma unroll
                for (int r = 0; r < 4; r++) {
                    int row = rowBase + mB + i * 16 + q * 4 + r;
                    float v = acc[i][j][r];
                    if (which <= 1) v = fmaxf(v, 0.f);
                    else if (which == 3) v = 1.f / (1.f + expf(-(v + bg[col])));
                    Out[(size_t)row * 512 + col] = f2bf(v);
                }
            }
    } else {
        float* __restrict__ Out = (float*)O0v;
#pragma unroll
        for (int i = 0; i < FM; i++)
#pragma unroll
            for (int j = 0; j < FN; j++) {
                int col = matCol + nB + j * 16 + ln;
#pragma unroll
                for (int r = 0; r < 4; r++) {
                    int row = rowBase + mB + i * 16 + q * 4 + r;
                    Out[(size_t)row * 512 + col] = acc[i][j][r];
                }
            }
    }
}

// ---------------------------------------------------------------------------
// Per-chunk KV outer-product local sums. bf16 in, bf16 Sst out, f32 Zst.
// ---------------------------------------------------------------------------
__global__ __launch_bounds__(256) void k_chunk_kv(
    const ushort* __restrict__ Kg, const ushort* __restrict__ Vg,
    ushort* __restrict__ Sst, float* __restrict__ Zst)
{
    __shared__ __align__(16) float Kb[C_ * 64];
    __shared__ __align__(16) float Vb[C_ * 64];
    __shared__ float cosA[C_], sinA[C_];

    const int blk = blockIdx.x;
    const int bh = blk >> 5, g = blk & 31;
    const int b = bh >> 3, h = bh & 7;
    const int tid = threadIdx.x;
    const int rBase = b * T_ + g * C_;
    const int colB = h * DK_;

    {   // 2048 elems per array; 256 threads x 8 (uint4 of bf16)
        int row = tid >> 3, c8 = (tid & 7) * 8;
        size_t ga = (size_t)(rBase + row) * D_ + colB + c8;
        uint4 kraw = *(const uint4*)&Kg[ga];
        uint4 vraw = *(const uint4*)&Vg[ga];
        const ushort* kp = (const ushort*)&kraw;
        const ushort* vp = (const ushort*)&vraw;
#pragma unroll
        for (int u = 0; u < 8; u++) {
            Kb[row * 64 + c8 + u] = bf2f(kp[u]);
            Vb[row * 64 + c8 + u] = bf2f(vp[u]);
        }
    }
    if (tid < C_) {
        float a = (float)(g * C_ + tid) * PI_OVER_2T;
        cosA[tid] = cosf(a); sinA[tid] = sinf(a);
    }
    __syncthreads();

    const int d = tid >> 2;
    const int e0 = (tid & 3) * 16;
    float sc[16], ss[16];
#pragma unroll
    for (int u = 0; u < 16; u++) { sc[u] = 0.f; ss[u] = 0.f; }
    float zc = 0.f, zs = 0.f;

    for (int t = 0; t < C_; t++) {
        float kk = Kb[t * 64 + d];
        float kc = kk * cosA[t], ks = kk * sinA[t];
        zc += kc; zs += ks;
#pragma unroll
        for (int u = 0; u < 4; u++) {
            float4 v4 = *(const float4*)&Vb[t * 64 + e0 + 4 * u];
            sc[4*u+0] += kc * v4.x; sc[4*u+1] += kc * v4.y;
            sc[4*u+2] += kc * v4.z; sc[4*u+3] += kc * v4.w;
            ss[4*u+0] += ks * v4.x; ss[4*u+1] += ks * v4.y;
            ss[4*u+2] += ks * v4.z; ss[4*u+3] += ks * v4.w;
        }
    }

    ushort* Sp = Sst + (size_t)blk * 8192;
    ushort pk[16];
#pragma unroll
    for (int u = 0; u < 16; u++) pk[u] = f2bf(sc[u]);
    *(uint4*)&Sp[d * 64 + e0] = *(uint4*)&pk[0];
    *(uint4*)&Sp[d * 64 + e0 + 8] = *(uint4*)&pk[8];
#pragma unroll
    for (int u = 0; u < 16; u++) pk[u] = f2bf(ss[u]);
    *(uint4*)&Sp[4096 + d * 64 + e0] = *(uint4*)&pk[0];
    *(uint4*)&Sp[4096 + d * 64 + e0 + 8] = *(uint4*)&pk[8];

    if ((tid & 3) == 0) {
        Zst[(size_t)blk * 128 + d] = zc;
        Zst[(size_t)blk * 128 + 64 + d] = zs;
    }
}

// ---------------------------------------------------------------------------
// Fused exclusive chunk-scan: Sst bf16 (32768 lanes x4) + Zst f32 (512 lanes x4).
// ---------------------------------------------------------------------------
__global__ __launch_bounds__(256) void k_scan(
    ushort* __restrict__ Sst, float* __restrict__ Zst)
{
    int id = blockIdx.x * 256 + threadIdx.x;
    if (id < 32768) {
        int bh = id >> 11, i4 = (id & 2047) * 4;
        float4 run = make_float4(0.f, 0.f, 0.f, 0.f);
        for (int g = 0; g < G_; g++) {
            ushort4* a = (ushort4*)&Sst[(size_t)(bh * G_ + g) * 8192 + i4];
            ushort4 t = *a;
            ushort4 o;
            o.x = f2bf(run.x); o.y = f2bf(run.y);
            o.z = f2bf(run.z); o.w = f2bf(run.w);
            *a = o;
            run.x += bf2f(t.x); run.y += bf2f(t.y);
            run.z += bf2f(t.z); run.w += bf2f(t.w);
        }
    } else {
        int id2 = id - 32768;
        if (id2 >= 512) return;
        int bh = id2 >> 5, i4 = (id2 & 31) * 4;
        float4 run = make_float4(0.f, 0.f, 0.f, 0.f);
        for (int g = 0; g < G_; g++) {
            float4* a = (float4*)&Zst[(size_t)(bh * G_ + g) * 128 + i4];
            float4 t = *a;
            *a = run;
            run.x += t.x; run.y += t.y; run.z += t.z; run.w += t.w;
        }
    }
}

// ---------------------------------------------------------------------------
// Per-chunk output (fp32 math, bf16 global I/O), writes bf16 Opre.
// ---------------------------------------------------------------------------
__global__ __launch_bounds__(256) void k_out_chunk(
    const ushort* __restrict__ Qg, const ushort* __restrict__ Kg,
    const ushort* __restrict__ Vg, const ushort* __restrict__ Gg,
    const ushort* __restrict__ Sst, const float* __restrict__ Zst,
    ushort* __restrict__ Op)
{
    __shared__ __align__(16) float Qb[C_ * 68];
    __shared__ __align__(16) float R1[64 * 68];
    __shared__ __align__(16) float Scb[64 * 68];
    __shared__ __align__(16) float Ssb[64 * 68];
    __shared__ __align__(16) float Pb[C_ * 36];
    __shared__ float cosA[C_], sinA[C_], zinv[C_], zcb[64], zsb[64];

    const int blk = blockIdx.x;
    const int bh = blk >> 5, g = blk & 31;
    const int b = bh >> 3, h = bh & 7;
    const int tid = threadIdx.x;
    const int rBase = b * T_ + g * C_;
    const int colB = h * DK_;

    // ---- phase 0: Q, K^T (bf16 global -> f32 LDS), Sc/Ss prefix, z, cos/sin
    {
        int row = tid >> 3, c8 = (tid & 7) * 8;
        size_t ga = (size_t)(rBase + row) * D_ + colB + c8;
        uint4 qraw = *(const uint4*)&Qg[ga];
        uint4 kraw = *(const uint4*)&Kg[ga];
        const ushort* qp = (const ushort*)&qraw;
        const ushort* kp = (const ushort*)&kraw;
#pragma unroll
        for (int u = 0; u < 8; u++) {
            Qb[row * 68 + c8 + u] = bf2f(qp[u]);
            R1[(c8 + u) * 36 + row] = bf2f(kp[u]);
        }
    }
    const ushort* Sbase = Sst + (size_t)blk * 8192;
    for (int v = tid; v < 512; v += 256) {   // Sc: 4096 elems
        int d = v >> 3, e8 = (v & 7) * 8;
        uint4 raw = *(const uint4*)&Sbase[d * 64 + e8];
        const ushort* sp = (const ushort*)&raw;
#pragma unroll
        for (int u = 0; u < 8; u++) Scb[d * 68 + e8 + u] = bf2f(sp[u]);
    }
    for (int v = tid; v < 512; v += 256) {   // Ss
        int d = v >> 3, e8 = (v & 7) * 8;
        uint4 raw = *(const uint4*)&Sbase[4096 + d * 64 + e8];
        const ushort* sp = (const ushort*)&raw;
#pragma unroll
        for (int u = 0; u < 8; u++) Ssb[d * 68 + e8 + u] = bf2f(sp[u]);
    }
    if (tid < 64) {
        zcb[tid] = Zst[(size_t)blk * 128 + tid];
    } else if (tid < 128) {
        zsb[tid - 64] = Zst[(size_t)blk * 128 + 64 + (tid - 64)];
    } else if (tid < 160) {
        int t = tid - 128;
        float a = (float)(g * C_ + t) * PI_OVER_2T;
        cosA[t] = cosf(a); sinA[t] = sinf(a);
    }
    __syncthreads();

    // ---- phase 1: P[t][s] = (Q[t].K[s]) * cos(a_t - a_s), causal-masked
    {
        const int t = tid >> 3;
        const int s4 = (tid & 7) * 4;
        float a0 = 0.f, a1 = 0.f, a2 = 0.f, a3 = 0.f;
#pragma unroll 8
        for (int k = 0; k < 64; k++) {
            float qv = Qb[t * 68 + k];
            float4 kv = *(const float4*)&R1[k * 36 + s4];
            a0 += qv * kv.x; a1 += qv * kv.y; a2 += qv * kv.z; a3 += qv * kv.w;
        }
        float ctt = cosA[t], stt = sinA[t];
        float r[4] = {a0, a1, a2, a3};
        float pr[4];
#pragma unroll
        for (int u = 0; u < 4; u++) {
            int s = s4 + u;
            float w = (s <= t) ? (ctt * cosA[s] + stt * sinA[s]) : 0.f;
            pr[u] = r[u] * w;
        }
        *(float4*)&Pb[t * 36 + s4] = make_float4(pr[0], pr[1], pr[2], pr[3]);
    }
    __syncthreads();

    // ---- phase 2: V into R1 (K^T dead), z and 1/z
    {
        int row = tid >> 3, c8 = (tid & 7) * 8;
        uint4 vraw = *(const uint4*)&Vg[(size_t)(rBase + row) * D_ + colB + c8];
        const ushort* vp = (const ushort*)&vraw;
#pragma unroll
        for (int u = 0; u < 8; u++) R1[row * 68 + c8 + u] = bf2f(vp[u]);
    }
    if (tid < C_) {
        const int t = tid;
        float ctt = cosA[t], stt = sinA[t];
        float z = 0.f;
        for (int d = 0; d < 64; d++)
            z += Qb[t * 68 + d] * (ctt * zcb[d] + stt * zsb[d]);
        for (int s = 0; s < C_; s++)
            z += Pb[t * 36 + s];
        zinv[t] = 1.f / fmaxf(z, 1e-6f);
    }
    __syncthreads();

    // ---- phase 3
    {
        const int t = tid >> 3;
        const int e0 = (tid & 7) * 8;
        float o[8];
#pragma unroll
        for (int u = 0; u < 8; u++) o[u] = 0.f;
        float ctt = cosA[t], stt = sinA[t];
#pragma unroll 4
        for (int d = 0; d < 64; d++) {
            float qv = Qb[t * 68 + d];
            float qc = qv * ctt, qs = qv * stt;
            float4 sc0 = *(const float4*)&Scb[d * 68 + e0];
            float4 sc1 = *(const float4*)&Scb[d * 68 + e0 + 4];
            float4 ss0 = *(const float4*)&Ssb[d * 68 + e0];
            float4 ss1 = *(const float4*)&Ssb[d * 68 + e0 + 4];
            o[0] += qc * sc0.x + qs * ss0.x;
            o[1] += qc * sc0.y + qs * ss0.y;
            o[2] += qc * sc0.z + qs * ss0.z;
            o[3] += qc * sc0.w + qs * ss0.w;
            o[4] += qc * sc1.x + qs * ss1.x;
            o[5] += qc * sc1.y + qs * ss1.y;
            o[6] += qc * sc1.z + qs * ss1.z;
            o[7] += qc * sc1.w + qs * ss1.w;
        }
#pragma unroll 4
        for (int s = 0; s < C_; s++) {
            float p = Pb[t * 36 + s];
            float4 v0 = *(const float4*)&R1[s * 68 + e0];
            float4 v1 = *(const float4*)&R1[s * 68 + e0 + 4];
            o[0] += p * v0.x; o[1] += p * v0.y;
            o[2] += p * v0.z; o[3] += p * v0.w;
            o[4] += p * v1.x; o[5] += p * v1.y;
            o[6] += p * v1.z; o[7] += p * v1.w;
        }
        const float zi = zinv[t];
        size_t go = (size_t)(rBase + t) * D_ + colB + e0;
        uint4 graw = *(const uint4*)&Gg[go];
        const ushort* gp = (const ushort*)&graw;
        ushort r8[8];
#pragma unroll
        for (int u = 0; u < 8; u++) r8[u] = f2bf(o[u] * zi * bf2f(gp[u]));
        *(uint4*)&Op[go] = *(uint4*)r8;
    }
}

// ---------------------------------------------------------------------------
extern "C" void kernel_launch(void* const* d_in, const int* in_sizes, int n_in,
                              void* d_out, int out_size, void* d_ws, size_t ws_size,
                              hipStream_t stream)
{
    const float* x  = (const float*)d_in[0];
    const float* Wq = (const float*)d_in[1];
    const float* Wk = (const float*)d_in[2];
    const float* Wv = (const float*)d_in[3];
    const float* Wo = (const float*)d_in[4];
    const float* Wg = (const float*)d_in[5];
    const float* bg = (const float*)d_in[6];
    float* out = (float*)d_out;

    ushort* wsu = (ushort*)d_ws;
    ushort* xb    = wsu;                   // 1M bf16
    ushort* WtAll = xb + 1048576;          // 5*256K bf16
    ushort* Qg    = WtAll + 1310720;       // 1M bf16 each
    ushort* Kg    = Qg + 1048576;
    ushort* Vg    = Kg + 1048576;
    ushort* Gg    = Vg + 1048576;
    ushort* Sst   = Gg + 1048576;          // 4M bf16
    ushort* Opb   = Sst + 4194304;         // 1M bf16
    float*  Zst   = (float*)(Opb + 1048576);  // 64K f32 (16B-aligned)

    dim3 blk(256);
    k_conv<<<dim3(1344), blk, 0, stream>>>(x, Wq, Wk, Wv, Wg, Wo, xb, WtAll);
    k_gemm<0, 128, 64><<<dim3(32, 16), blk, 0, stream>>>(
        xb, WtAll, bg, Qg, Kg, Vg, Gg);
    k_chunk_kv<<<dim3(NBH_ * G_), blk, 0, stream>>>(Kg, Vg, Sst, Zst);
    k_scan<<<dim3(130), blk, 0, stream>>>(Sst, Zst);
    k_out_chunk<<<dim3(NBH_ * G_), blk, 0, stream>>>(
        Qg, Kg, Vg, Gg, Sst, Zst, Opb);
    k_gemm<1, 64, 64><<<dim3(8, 32), blk, 0, stream>>>(
        Opb, WtAll + (size_t)4 * 262144, nullptr, out, nullptr, nullptr, nullptr);
}

// Round 5
// 117.714 us; speedup vs baseline: 1.8194x; 1.0774x over previous
//
#include <hip/hip_runtime.h>
#include <math.h>

// Problem constants
#define B_ 2
#define T_ 1024
#define D_ 512
#define H_ 8
#define DK_ 64
#define NBH_ 16          // B*H
#define C_ 32            // chunk length
#define G_ 32            // T/C chunks

#define PI_OVER_2T 0.00153398078788564122971808758949f  /* pi/2048 */

typedef float f32x4 __attribute__((ext_vector_type(4)));
typedef short s16x8 __attribute__((ext_vector_type(8)));

__device__ __forceinline__ ushort f2bf(float x) {
    unsigned u = __float_as_uint(x);
    unsigned r = (u + 0x7fffu + ((u >> 16) & 1u)) >> 16;   // RNE
    return (ushort)r;
}
__device__ __forceinline__ float bf2f(ushort u) {
    return __uint_as_float((unsigned)u << 16);
}
// scale all 8 bf16 lanes of an A-frag by a scalar (f32 round-trip)
__device__ __forceinline__ s16x8 bscale(s16x8 v, float s) {
    s16x8 r;
#pragma unroll
    for (int u = 0; u < 8; u++)
        r[u] = (short)f2bf(bf2f((ushort)v[u]) * s);
    return r;
}

// async global->LDS, 16B/lane; LDS dest must be tid-contiguous (m104).
__device__ __forceinline__ void async16(void* lds, const void* g) {
    __builtin_amdgcn_global_load_lds(
        (const __attribute__((address_space(1))) void*)g,
        (__attribute__((address_space(3))) void*)lds, 16, 0, 0);
}

// ---------------------------------------------------------------------------
// Fused convert kernel.
// blocks 0..1023: x (2048x512 f32) -> xb bf16.
// blocks 1024..1343: 5 weights (512x512 f32 (k,n)) -> WtAll bf16 (n,k).
// ---------------------------------------------------------------------------
__global__ __launch_bounds__(256) void k_conv(
    const float* __restrict__ x,
    const float* __restrict__ Wq, const float* __restrict__ Wk,
    const float* __restrict__ Wv, const float* __restrict__ Wg,
    const float* __restrict__ Wo,
    ushort* __restrict__ xb, ushort* __restrict__ WtAll)
{
    __shared__ float Ts[64][65];
    const int bx = blockIdx.x;
    const int tid = threadIdx.x;
    if (bx < 1024) {
        int i = (bx * 256 + tid) * 4;
        float4 v = *(const float4*)&x[i];
        ushort4 o;
        o.x = f2bf(v.x); o.y = f2bf(v.y); o.z = f2bf(v.z); o.w = f2bf(v.w);
        *(ushort4*)&xb[i] = o;
        return;
    }
    const int bid = bx - 1024;
    const int mi = bid >> 6;
    const int t64 = bid & 63;
    const float* __restrict__ W = (mi == 0) ? Wq : (mi == 1) ? Wk
                                 : (mi == 2) ? Wv : (mi == 3) ? Wg : Wo;
    const int tr = t64 >> 3, tc = t64 & 7;
#pragma unroll
    for (int p = 0; p < 4; p++) {
        int row = p * 16 + (tid >> 4);
        int c4 = (tid & 15) * 4;
        float4 v = *(const float4*)&W[(size_t)(tr * 64 + row) * 512 + tc * 64 + c4];
        Ts[row][c4 + 0] = v.x; Ts[row][c4 + 1] = v.y;
        Ts[row][c4 + 2] = v.z; Ts[row][c4 + 3] = v.w;
    }
    __syncthreads();
    const int nl = tid >> 2, kc = (tid & 3) * 16;
    ushort buf[16];
#pragma unroll
    for (int u = 0; u < 16; u++) buf[u] = f2bf(Ts[kc + u][nl]);
    ushort* dst = WtAll + (size_t)mi * 262144 + (size_t)(tc * 64 + nl) * 512
                  + tr * 64 + kc;
    *(uint4*)dst = *(uint4*)&buf[0];
    *(uint4*)(dst + 8) = *(uint4*)&buf[8];
}

// ---------------------------------------------------------------------------
// bf16 MFMA GEMM, double-buffered K-loop (unchanged from round 4).
// ---------------------------------------------------------------------------
template<int MODE, int TM, int TN>
__global__ __launch_bounds__(256) void k_gemm(
    const ushort* __restrict__ A, const ushort* __restrict__ Bt,
    const float* __restrict__ bg,
    void* __restrict__ O0v, void* __restrict__ O1v,
    void* __restrict__ O2v, void* __restrict__ O3v)
{
    constexpr int WM = TM / 2, WN = TN / 2;
    constexpr int FM = WM / 16, FN = WN / 16;
    constexpr int NA = (TM * 32) / 2048;
    constexpr int NB = (TN * 32) / 2048;

    __shared__ ushort As[2][TM * 32];
    __shared__ ushort Bs[2][TN * 32];

    const int tid = threadIdx.x;
    const int ct = blockIdx.x;
    const int rowBase = blockIdx.y * TM;

    const ushort* __restrict__ Bmat;
    int which = 0, matCol;
    if (MODE == 0) {
        which = ct / (512 / TN);
        matCol = (ct % (512 / TN)) * TN;
        Bmat = Bt + (size_t)which * 262144;
    } else {
        matCol = ct * TN;
        Bmat = Bt;
    }

    const int wave = tid >> 6, lane = tid & 63;
    const int q = lane >> 4, ln = lane & 15;
    const int mB = (wave >> 1) * WM, nB = (wave & 1) * WN;

    int fuA[NA], fuB[NB];
    const ushort* gA[NA];
    const ushort* gB[NB];
#pragma unroll
    for (int u = 0; u < NA; u++) {
        int fu = tid * 8 + u * 2048;
        int r = fu >> 5;
        int c = ((((fu >> 3) & 3) ^ ((r >> 1) & 3))) * 8;
        fuA[u] = fu;
        gA[u] = A + (size_t)(rowBase + r) * 512 + c;
    }
#pragma unroll
    for (int u = 0; u < NB; u++) {
        int fu = tid * 8 + u * 2048;
        int r = fu >> 5;
        int c = ((((fu >> 3) & 3) ^ ((r >> 1) & 3))) * 8;
        fuB[u] = fu;
        gB[u] = Bmat + (size_t)(matCol + r) * 512 + c;
    }

    f32x4 acc[FM][FN];
#pragma unroll
    for (int i = 0; i < FM; i++)
#pragma unroll
        for (int j = 0; j < FN; j++) acc[i][j] = (f32x4){0.f, 0.f, 0.f, 0.f};

    int aoff[FM], boff[FN];
#pragma unroll
    for (int i = 0; i < FM; i++) {
        int ra = mB + i * 16 + ln;
        aoff[i] = ra * 32 + ((q ^ ((ra >> 1) & 3)) * 8);
    }
#pragma unroll
    for (int j = 0; j < FN; j++) {
        int rb = nB + j * 16 + ln;
        boff[j] = rb * 32 + ((q ^ ((rb >> 1) & 3)) * 8);
    }

#pragma unroll
    for (int u = 0; u < NA; u++) async16(&As[0][fuA[u]], gA[u]);
#pragma unroll
    for (int u = 0; u < NB; u++) async16(&Bs[0][fuB[u]], gB[u]);

    int cur = 0;
    for (int kb = 0; kb < 512; kb += 32) {
        __syncthreads();
        if (kb + 32 < 512) {
#pragma unroll
            for (int u = 0; u < NA; u++)
                async16(&As[cur ^ 1][fuA[u]], gA[u] + kb + 32);
#pragma unroll
            for (int u = 0; u < NB; u++)
                async16(&Bs[cur ^ 1][fuB[u]], gB[u] + kb + 32);
        }
        s16x8 af[FM], bf[FN];
#pragma unroll
        for (int i = 0; i < FM; i++) af[i] = *(const s16x8*)&As[cur][aoff[i]];
#pragma unroll
        for (int j = 0; j < FN; j++) bf[j] = *(const s16x8*)&Bs[cur][boff[j]];
#pragma unroll
        for (int i = 0; i < FM; i++)
#pragma unroll
            for (int j = 0; j < FN; j++)
                acc[i][j] = __builtin_amdgcn_mfma_f32_16x16x32_bf16(
                    af[i], bf[j], acc[i][j], 0, 0, 0);
        cur ^= 1;
    }

    if (MODE == 0) {
        ushort* __restrict__ Out = (which == 0) ? (ushort*)O0v
                                  : (which == 1) ? (ushort*)O1v
                                  : (which == 2) ? (ushort*)O2v : (ushort*)O3v;
#pragma unroll
        for (int i = 0; i < FM; i++)
#pragma unroll
            for (int j = 0; j < FN; j++) {
                int col = matCol + nB + j * 16 + ln;
#pragma unroll
                for (int r = 0; r < 4; r++) {
                    int row = rowBase + mB + i * 16 + q * 4 + r;
                    float v = acc[i][j][r];
                    if (which <= 1) v = fmaxf(v, 0.f);
                    else if (which == 3) v = 1.f / (1.f + expf(-(v + bg[col])));
                    Out[(size_t)row * 512 + col] = f2bf(v);
                }
            }
    } else {
        float* __restrict__ Out = (float*)O0v;
#pragma unroll
        for (int i = 0; i < FM; i++)
#pragma unroll
            for (int j = 0; j < FN; j++) {
                int col = matCol + nB + j * 16 + ln;
#pragma unroll
                for (int r = 0; r < 4; r++) {
                    int row = rowBase + mB + i * 16 + q * 4 + r;
                    Out[(size_t)row * 512 + col] = acc[i][j][r];
                }
            }
    }
}

// ---------------------------------------------------------------------------
// Per-chunk KV sums via MFMA.  Stores ScT[e][d] (TRANSPOSED) so the
// out-chunk kernel can read B-frags (contraction-fastest) straight from
// global.  ScT[e][d] = sum_t V[t][e] * Kc[t][d];  M=e, N=d, K=t=32.
// One LDS transpose of Kc/Ks/V (both MFMA operands need t-fastest).
// ---------------------------------------------------------------------------
__global__ __launch_bounds__(256) void k_chunk_kv(
    const ushort* __restrict__ Kg, const ushort* __restrict__ Vg,
    ushort* __restrict__ Sst, float* __restrict__ Zst)
{
    __shared__ ushort KcT[64 * 40];   // [d][t] pad 40 -> 2-way LDS (free)
    __shared__ ushort KsT[64 * 40];
    __shared__ ushort VT [64 * 40];   // [e][t]

    const int blk = blockIdx.x;
    const int bh = blk >> 5, g = blk & 31;
    const int b = bh >> 3, h = bh & 7;
    const int tid = threadIdx.x;
    const int rBase = b * T_ + g * C_;
    const int colB = h * DK_;

    // stage + transpose: thread -> row t = tid>>3, cols c8..c8+7
    {
        int row = tid >> 3, c8 = (tid & 7) * 8;
        float a = (float)(g * C_ + row) * PI_OVER_2T;
        float ca = cosf(a), sa = sinf(a);
        size_t ga = (size_t)(rBase + row) * D_ + colB + c8;
        uint4 kraw = *(const uint4*)&Kg[ga];
        uint4 vraw = *(const uint4*)&Vg[ga];
        const ushort* kp = (const ushort*)&kraw;
        const ushort* vp = (const ushort*)&vraw;
#pragma unroll
        for (int u = 0; u < 8; u++) {
            float kf = bf2f(kp[u]);
            KcT[(c8 + u) * 40 + row] = f2bf(kf * ca);
            KsT[(c8 + u) * 40 + row] = f2bf(kf * sa);
            VT [(c8 + u) * 40 + row] = vp[u];
        }
    }
    __syncthreads();

    // z sums (threads 0..127): zc[d] = sum_t Kc[t][d]
    if (tid < 128) {
        int d = tid & 63;
        const ushort* src = (tid < 64) ? KcT : KsT;
        float zsum = 0.f;
#pragma unroll
        for (int t = 0; t < C_; t++) zsum += bf2f(src[d * 40 + t]);
        Zst[(size_t)blk * 128 + tid] = zsum;
    }

    // MFMA: wave w computes ScT rows e in [w*16, w*16+16)
    const int wave = tid >> 6, lane = tid & 63;
    const int q = lane >> 4, ln = lane & 15;
    s16x8 av = *(const s16x8*)&VT[(wave * 16 + ln) * 40 + q * 8];
    ushort* Sp = Sst + (size_t)blk * 8192;
#pragma unroll
    for (int nj = 0; nj < 4; nj++) {
        s16x8 bc = *(const s16x8*)&KcT[(nj * 16 + ln) * 40 + q * 8];
        s16x8 bs = *(const s16x8*)&KsT[(nj * 16 + ln) * 40 + q * 8];
        f32x4 ac = __builtin_amdgcn_mfma_f32_16x16x32_bf16(
            av, bc, (f32x4){0.f, 0.f, 0.f, 0.f}, 0, 0, 0);
        f32x4 as = __builtin_amdgcn_mfma_f32_16x16x32_bf16(
            av, bs, (f32x4){0.f, 0.f, 0.f, 0.f}, 0, 0, 0);
        // C-layout: col d = nj*16+ln, row e = wave*16 + q*4 + r
#pragma unroll
        for (int r = 0; r < 4; r++) {
            int e = wave * 16 + q * 4 + r;
            int d = nj * 16 + ln;
            Sp[e * 64 + d] = f2bf(ac[r]);
            Sp[4096 + e * 64 + d] = f2bf(as[r]);
        }
    }
}

// ---------------------------------------------------------------------------
// Fused exclusive chunk-scan: Sst bf16 + Zst f32 (elementwise; layout-agnostic)
// ---------------------------------------------------------------------------
__global__ __launch_bounds__(256) void k_scan(
    ushort* __restrict__ Sst, float* __restrict__ Zst)
{
    int id = blockIdx.x * 256 + threadIdx.x;
    if (id < 32768) {
        int bh = id >> 11, i4 = (id & 2047) * 4;
        float4 run = make_float4(0.f, 0.f, 0.f, 0.f);
        for (int g = 0; g < G_; g++) {
            ushort4* a = (ushort4*)&Sst[(size_t)(bh * G_ + g) * 8192 + i4];
            ushort4 t = *a;
            ushort4 o;
            o.x = f2bf(run.x); o.y = f2bf(run.y);
            o.z = f2bf(run.z); o.w = f2bf(run.w);
            *a = o;
            run.x += bf2f(t.x); run.y += bf2f(t.y);
            run.z += bf2f(t.z); run.w += bf2f(t.w);
        }
    } else {
        int id2 = id - 32768;
        if (id2 >= 512) return;
        int bh = id2 >> 5, i4 = (id2 & 31) * 4;
        float4 run = make_float4(0.f, 0.f, 0.f, 0.f);
        for (int g = 0; g < G_; g++) {
            float4* a = (float4*)&Zst[(size_t)(bh * G_ + g) * 128 + i4];
            float4 t = *a;
            *a = run;
            run.x += t.x; run.y += t.y; run.z += t.z; run.w += t.w;
        }
    }
}

// ---------------------------------------------------------------------------
// Per-chunk output via MFMA.
//  P = Q@K^T (A/B frags DIRECT from global; [t][d] is contraction-fastest),
//  masked+cos-weighted in C-layout regs, -> LDS (bf16) -> A-frag for P@V.
//  o = Qc@Sc_pre + Qs@Ss_pre + P@V; Sc/Ss B-frags DIRECT from scanned ScT.
//  z = rowsum(P) + Qc.zc_pre + Qs.zs_pre  (shuffle-reduced).
// ---------------------------------------------------------------------------
__global__ __launch_bounds__(256) void k_out_chunk(
    const ushort* __restrict__ Qg, const ushort* __restrict__ Kg,
    const ushort* __restrict__ Vg, const ushort* __restrict__ Gg,
    const ushort* __restrict__ Sst, const float* __restrict__ Zst,
    ushort* __restrict__ Op)
{
    __shared__ ushort VT[64 * 40];    // V^T [e][s]  (B-frags for P@V)
    __shared__ ushort Pb[32 * 40];    // P  [t][s]   (A-frags for P@V)
    __shared__ float zinv[32];

    const int blk = blockIdx.x;
    const int bh = blk >> 5, g = blk & 31;
    const int b = bh >> 3, h = bh & 7;
    const int tid = threadIdx.x;
    const int rBase = b * T_ + g * C_;
    const int colB = h * DK_;
    const int wave = tid >> 6, lane = tid & 63;
    const int q = lane >> 4, ln = lane & 15;

    // ---- stage V^T (all threads)
    {
        int row = tid >> 3, c8 = (tid & 7) * 8;
        uint4 vraw = *(const uint4*)&Vg[(size_t)(rBase + row) * D_ + colB + c8];
        const ushort* vp = (const ushort*)&vraw;
#pragma unroll
        for (int u = 0; u < 8; u++) VT[(c8 + u) * 40 + row] = vp[u];
    }

    // ---- P phase: wave w -> t-block mi=w>>1, s-block njp=w&1
    const int mi = wave >> 1, njp = wave & 1;
    const ushort* qrow = Qg + (size_t)(rBase + mi * 16 + ln) * D_ + colB;
    s16x8 aq0 = *(const s16x8*)&qrow[q * 8];
    s16x8 aq1 = *(const s16x8*)&qrow[32 + q * 8];
    {
        const ushort* krow = Kg + (size_t)(rBase + njp * 16 + ln) * D_ + colB;
        s16x8 bk0 = *(const s16x8*)&krow[q * 8];
        s16x8 bk1 = *(const s16x8*)&krow[32 + q * 8];
        f32x4 pacc = __builtin_amdgcn_mfma_f32_16x16x32_bf16(
            aq0, bk0, (f32x4){0.f, 0.f, 0.f, 0.f}, 0, 0, 0);
        pacc = __builtin_amdgcn_mfma_f32_16x16x32_bf16(aq1, bk1, pacc, 0, 0, 0);
        int sl = njp * 16 + ln;
        float as_ = (float)(g * C_ + sl) * PI_OVER_2T;
        float cs_ = cosf(as_), ss_ = sinf(as_);
#pragma unroll
        for (int r = 0; r < 4; r++) {
            int tl = mi * 16 + q * 4 + r;
            float at = (float)(g * C_ + tl) * PI_OVER_2T;
            float w = (sl <= tl) ? (cosf(at) * cs_ + sinf(at) * ss_) : 0.f;
            Pb[tl * 40 + sl] = f2bf(pacc[r] * w);
        }
    }
    __syncthreads();

    // ---- z phase: t = tid>>3 (0..31), sub = tid&7
    {
        int t = tid >> 3, sub = tid & 7;
        uint4 qraw = *(const uint4*)&Qg[(size_t)(rBase + t) * D_ + colB + sub * 8];
        const ushort* qp = (const ushort*)&qraw;
        const float* zcp = Zst + (size_t)blk * 128 + sub * 8;
        float4 zc0 = *(const float4*)&zcp[0];
        float4 zc1 = *(const float4*)&zcp[4];
        float4 zs0 = *(const float4*)&zcp[64];
        float4 zs1 = *(const float4*)&zcp[68];
        float pc = 0.f, ps = 0.f;
        float zcv[8] = {zc0.x, zc0.y, zc0.z, zc0.w, zc1.x, zc1.y, zc1.z, zc1.w};
        float zsv[8] = {zs0.x, zs0.y, zs0.z, zs0.w, zs1.x, zs1.y, zs1.z, zs1.w};
#pragma unroll
        for (int u = 0; u < 8; u++) {
            float qf = bf2f(qp[u]);
            pc += qf * zcv[u]; ps += qf * zsv[u];
        }
        float pr = 0.f;
#pragma unroll
        for (int u = 0; u < 4; u++) pr += bf2f(Pb[t * 40 + sub * 4 + u]);
#pragma unroll
        for (int m = 1; m < 8; m <<= 1) {
            pc += __shfl_xor(pc, m);
            ps += __shfl_xor(ps, m);
            pr += __shfl_xor(pr, m);
        }
        if (sub == 0) {
            float at = (float)(g * C_ + t) * PI_OVER_2T;
            float z = cosf(at) * pc + sinf(at) * ps + pr;
            zinv[t] = 1.f / fmaxf(z, 1e-6f);
        }
    }
    __syncthreads();

    // ---- o phase: wave w -> t-block mi (same as P), n-blocks {2*(w&1), +1}
    {
        float am = (float)(g * C_ + mi * 16 + ln) * PI_OVER_2T;
        float cm = cosf(am), sm = sinf(am);
        s16x8 aqc0 = bscale(aq0, cm), aqc1 = bscale(aq1, cm);
        s16x8 aqs0 = bscale(aq0, sm), aqs1 = bscale(aq1, sm);
        s16x8 pf = *(const s16x8*)&Pb[(mi * 16 + ln) * 40 + q * 8];  // K=32
        const ushort* Sp = Sst + (size_t)blk * 8192;
#pragma unroll
        for (int jj = 0; jj < 2; jj++) {
            int nj = 2 * (wave & 1) + jj;
            const ushort* scp = Sp + (nj * 16 + ln) * 64;
            s16x8 bc0 = *(const s16x8*)&scp[q * 8];
            s16x8 bc1 = *(const s16x8*)&scp[32 + q * 8];
            s16x8 bs0 = *(const s16x8*)&scp[4096 + q * 8];
            s16x8 bs1 = *(const s16x8*)&scp[4096 + 32 + q * 8];
            s16x8 bv  = *(const s16x8*)&VT[(nj * 16 + ln) * 40 + q * 8];
            f32x4 acc = __builtin_amdgcn_mfma_f32_16x16x32_bf16(
                pf, bv, (f32x4){0.f, 0.f, 0.f, 0.f}, 0, 0, 0);
            acc = __builtin_amdgcn_mfma_f32_16x16x32_bf16(aqc0, bc0, acc, 0, 0, 0);
            acc = __builtin_amdgcn_mfma_f32_16x16x32_bf16(aqc1, bc1, acc, 0, 0, 0);
            acc = __builtin_amdgcn_mfma_f32_16x16x32_bf16(aqs0, bs0, acc, 0, 0, 0);
            acc = __builtin_amdgcn_mfma_f32_16x16x32_bf16(aqs1, bs1, acc, 0, 0, 0);
#pragma unroll
            for (int r = 0; r < 4; r++) {
                int tl = mi * 16 + q * 4 + r;
                int e = nj * 16 + ln;
                size_t go = (size_t)(rBase + tl) * D_ + colB + e;
                float o = acc[r] * zinv[tl] * bf2f(Gg[go]);
                Op[go] = f2bf(o);
            }
        }
    }
}

// ---------------------------------------------------------------------------
extern "C" void kernel_launch(void* const* d_in, const int* in_sizes, int n_in,
                              void* d_out, int out_size, void* d_ws, size_t ws_size,
                              hipStream_t stream)
{
    const float* x  = (const float*)d_in[0];
    const float* Wq = (const float*)d_in[1];
    const float* Wk = (const float*)d_in[2];
    const float* Wv = (const float*)d_in[3];
    const float* Wo = (const float*)d_in[4];
    const float* Wg = (const float*)d_in[5];
    const float* bg = (const float*)d_in[6];
    float* out = (float*)d_out;

    ushort* wsu = (ushort*)d_ws;
    ushort* xb    = wsu;                   // 1M bf16
    ushort* WtAll = xb + 1048576;          // 5*256K bf16
    ushort* Qg    = WtAll + 1310720;       // 1M bf16 each
    ushort* Kg    = Qg + 1048576;
    ushort* Vg    = Kg + 1048576;
    ushort* Gg    = Vg + 1048576;
    ushort* Sst   = Gg + 1048576;          // 4M bf16 (ScT/SsT per chunk)
    ushort* Opb   = Sst + 4194304;         // 1M bf16
    float*  Zst   = (float*)(Opb + 1048576);  // 64K f32

    dim3 blk(256);
    k_conv<<<dim3(1344), blk, 0, stream>>>(x, Wq, Wk, Wv, Wg, Wo, xb, WtAll);
    k_gemm<0, 128, 64><<<dim3(32, 16), blk, 0, stream>>>(
        xb, WtAll, bg, Qg, Kg, Vg, Gg);
    k_chunk_kv<<<dim3(NBH_ * G_), blk, 0, stream>>>(Kg, Vg, Sst, Zst);
    k_scan<<<dim3(130), blk, 0, stream>>>(Sst, Zst);
    k_out_chunk<<<dim3(NBH_ * G_), blk, 0, stream>>>(
        Qg, Kg, Vg, Gg, Sst, Zst, Opb);
    k_gemm<1, 64, 64><<<dim3(8, 32), blk, 0, stream>>>(
        Opb, WtAll + (size_t)4 * 262144, nullptr, out, nullptr, nullptr, nullptr);
}

// Round 6
// 113.746 us; speedup vs baseline: 1.8828x; 1.0349x over previous
//
#include <hip/hip_runtime.h>
#include <math.h>

// Problem constants
#define B_ 2
#define T_ 1024
#define D_ 512
#define H_ 8
#define DK_ 64
#define NBH_ 16          // B*H
#define C_ 32            // chunk length
#define G_ 32            // T/C chunks

#define PI_OVER_2T 0.00153398078788564122971808758949f  /* pi/2048 */

typedef float f32x4 __attribute__((ext_vector_type(4)));
typedef short s16x8 __attribute__((ext_vector_type(8)));

__device__ __forceinline__ ushort f2bf(float x) {
    unsigned u = __float_as_uint(x);
    unsigned r = (u + 0x7fffu + ((u >> 16) & 1u)) >> 16;   // RNE
    return (ushort)r;
}
__device__ __forceinline__ float bf2f(ushort u) {
    return __uint_as_float((unsigned)u << 16);
}
__device__ __forceinline__ s16x8 bscale(s16x8 v, float s) {
    s16x8 r;
#pragma unroll
    for (int u = 0; u < 8; u++)
        r[u] = (short)f2bf(bf2f((ushort)v[u]) * s);
    return r;
}

// async global->LDS, 16B/lane; LDS dest must be tid-contiguous (m104).
__device__ __forceinline__ void async16(void* lds, const void* g) {
    __builtin_amdgcn_global_load_lds(
        (const __attribute__((address_space(1))) void*)g,
        (__attribute__((address_space(3))) void*)lds, 16, 0, 0);
}

// ---------------------------------------------------------------------------
// Fused convert kernel.
// blocks 0..1023: x (2048x512 f32) -> xb bf16.
// blocks 1024..1343: 5 weights (512x512 f32 (k,n)) -> WtAll bf16 (n,k).
// ---------------------------------------------------------------------------
__global__ __launch_bounds__(256) void k_conv(
    const float* __restrict__ x,
    const float* __restrict__ Wq, const float* __restrict__ Wk,
    const float* __restrict__ Wv, const float* __restrict__ Wg,
    const float* __restrict__ Wo,
    ushort* __restrict__ xb, ushort* __restrict__ WtAll)
{
    __shared__ float Ts[64][65];
    const int bx = blockIdx.x;
    const int tid = threadIdx.x;
    if (bx < 1024) {
        int i = (bx * 256 + tid) * 4;
        float4 v = *(const float4*)&x[i];
        ushort4 o;
        o.x = f2bf(v.x); o.y = f2bf(v.y); o.z = f2bf(v.z); o.w = f2bf(v.w);
        *(ushort4*)&xb[i] = o;
        return;
    }
    const int bid = bx - 1024;
    const int mi = bid >> 6;
    const int t64 = bid & 63;
    const float* __restrict__ W = (mi == 0) ? Wq : (mi == 1) ? Wk
                                 : (mi == 2) ? Wv : (mi == 3) ? Wg : Wo;
    const int tr = t64 >> 3, tc = t64 & 7;
#pragma unroll
    for (int p = 0; p < 4; p++) {
        int row = p * 16 + (tid >> 4);
        int c4 = (tid & 15) * 4;
        float4 v = *(const float4*)&W[(size_t)(tr * 64 + row) * 512 + tc * 64 + c4];
        Ts[row][c4 + 0] = v.x; Ts[row][c4 + 1] = v.y;
        Ts[row][c4 + 2] = v.z; Ts[row][c4 + 3] = v.w;
    }
    __syncthreads();
    const int nl = tid >> 2, kc = (tid & 3) * 16;
    ushort buf[16];
#pragma unroll
    for (int u = 0; u < 16; u++) buf[u] = f2bf(Ts[kc + u][nl]);
    ushort* dst = WtAll + (size_t)mi * 262144 + (size_t)(tc * 64 + nl) * 512
                  + tr * 64 + kc;
    *(uint4*)dst = *(uint4*)&buf[0];
    *(uint4*)(dst + 8) = *(uint4*)&buf[8];
}

// ---------------------------------------------------------------------------
// bf16 MFMA GEMM, double-buffered K-loop, templated BK.
// Swizzle: LDS slot s at row r holds global chunk s ^ ((r>>SH)&(CH-1)) so
// frag ds_read_b128 is 2-way bank-conflicted (free, m136).
//   BK=32: row=64B spans 16 banks -> SH=1, CH=4.
//   BK=64: row=128B spans all 32 banks -> SH=0, CH=8.
// ---------------------------------------------------------------------------
template<int MODE, int TM, int TN, int BK>
__global__ __launch_bounds__(256) void k_gemm(
    const ushort* __restrict__ A, const ushort* __restrict__ Bt,
    const float* __restrict__ bg,
    void* __restrict__ O0v, void* __restrict__ O1v,
    void* __restrict__ O2v, void* __restrict__ O3v)
{
    constexpr int WM = TM / 2, WN = TN / 2;
    constexpr int FM = WM / 16, FN = WN / 16;
    constexpr int CH = BK / 8;               // 16B chunks per LDS row
    constexpr int SH = (BK == 32) ? 1 : 0;
    constexpr int KS = BK / 32;              // MFMA k-steps per tile
    constexpr int NA = TM * BK / 2048;
    constexpr int NB = TN * BK / 2048;

    __shared__ ushort As[2][TM * BK];
    __shared__ ushort Bs[2][TN * BK];

    const int tid = threadIdx.x;
    const int ct = blockIdx.x;
    const int rowBase = blockIdx.y * TM;

    const ushort* __restrict__ Bmat;
    int which = 0, matCol;
    if (MODE == 0) {
        which = ct / (512 / TN);
        matCol = (ct % (512 / TN)) * TN;
        Bmat = Bt + (size_t)which * 262144;
    } else {
        matCol = ct * TN;
        Bmat = Bt;
    }

    const int wave = tid >> 6, lane = tid & 63;
    const int q = lane >> 4, ln = lane & 15;
    const int mB = (wave >> 1) * WM, nB = (wave & 1) * WN;

    int fuA[NA], fuB[NB];
    const ushort* gA[NA];
    const ushort* gB[NB];
#pragma unroll
    for (int u = 0; u < NA; u++) {
        int fu = tid * 8 + u * 2048;
        int r = fu / BK;
        int slot = (fu >> 3) & (CH - 1);
        int gc = slot ^ ((r >> SH) & (CH - 1));
        fuA[u] = fu;
        gA[u] = A + (size_t)(rowBase + r) * 512 + gc * 8;
    }
#pragma unroll
    for (int u = 0; u < NB; u++) {
        int fu = tid * 8 + u * 2048;
        int r = fu / BK;
        int slot = (fu >> 3) & (CH - 1);
        int gc = slot ^ ((r >> SH) & (CH - 1));
        fuB[u] = fu;
        gB[u] = Bmat + (size_t)(matCol + r) * 512 + gc * 8;
    }

    f32x4 acc[FM][FN];
#pragma unroll
    for (int i = 0; i < FM; i++)
#pragma unroll
        for (int j = 0; j < FN; j++) acc[i][j] = (f32x4){0.f, 0.f, 0.f, 0.f};

    int aoff[FM][KS], boff[FN][KS];
#pragma unroll
    for (int i = 0; i < FM; i++) {
        int ra = mB + i * 16 + ln;
#pragma unroll
        for (int ks = 0; ks < KS; ks++)
            aoff[i][ks] = ra * BK
                + (((ks * 4 + q) ^ ((ra >> SH) & (CH - 1))) * 8);
    }
#pragma unroll
    for (int j = 0; j < FN; j++) {
        int rb = nB + j * 16 + ln;
#pragma unroll
        for (int ks = 0; ks < KS; ks++)
            boff[j][ks] = rb * BK
                + (((ks * 4 + q) ^ ((rb >> SH) & (CH - 1))) * 8);
    }

#pragma unroll
    for (int u = 0; u < NA; u++) async16(&As[0][fuA[u]], gA[u]);
#pragma unroll
    for (int u = 0; u < NB; u++) async16(&Bs[0][fuB[u]], gB[u]);

    int cur = 0;
    for (int kb = 0; kb < 512; kb += BK) {
        __syncthreads();
        if (kb + BK < 512) {
#pragma unroll
            for (int u = 0; u < NA; u++)
                async16(&As[cur ^ 1][fuA[u]], gA[u] + kb + BK);
#pragma unroll
            for (int u = 0; u < NB; u++)
                async16(&Bs[cur ^ 1][fuB[u]], gB[u] + kb + BK);
        }
#pragma unroll
        for (int ks = 0; ks < KS; ks++) {
            s16x8 af[FM], bf[FN];
#pragma unroll
            for (int i = 0; i < FM; i++)
                af[i] = *(const s16x8*)&As[cur][aoff[i][ks]];
#pragma unroll
            for (int j = 0; j < FN; j++)
                bf[j] = *(const s16x8*)&Bs[cur][boff[j][ks]];
#pragma unroll
            for (int i = 0; i < FM; i++)
#pragma unroll
                for (int j = 0; j < FN; j++)
                    acc[i][j] = __builtin_amdgcn_mfma_f32_16x16x32_bf16(
                        af[i], bf[j], acc[i][j], 0, 0, 0);
        }
        cur ^= 1;
    }

    // epilogue: C/D layout col=lane&15, row=quad*4+reg (m89-verified)
    if (MODE == 0) {
        ushort* __restrict__ Out = (which == 0) ? (ushort*)O0v
                                  : (which == 1) ? (ushort*)O1v
                                  : (which == 2) ? (ushort*)O2v : (ushort*)O3v;
#pragma unroll
        for (int i = 0; i < FM; i++)
#pragma unroll
            for (int j = 0; j < FN; j++) {
                int col = matCol + nB + j * 16 + ln;
#pragma unroll
                for (int r = 0; r < 4; r++) {
                    int row = rowBase + mB + i * 16 + q * 4 + r;
                    float v = acc[i][j][r];
                    if (which <= 1) v = fmaxf(v, 0.f);
                    else if (which == 3) v = 1.f / (1.f + expf(-(v + bg[col])));
                    Out[(size_t)row * 512 + col] = f2bf(v);
                }
            }
    } else {
        float* __restrict__ Out = (float*)O0v;
#pragma unroll
        for (int i = 0; i < FM; i++)
#pragma unroll
            for (int j = 0; j < FN; j++) {
                int col = matCol + nB + j * 16 + ln;
#pragma unroll
                for (int r = 0; r < 4; r++) {
                    int row = rowBase + mB + i * 16 + q * 4 + r;
                    Out[(size_t)row * 512 + col] = acc[i][j][r];
                }
            }
    }
}

// ---------------------------------------------------------------------------
// Per-chunk KV sums via MFMA (stores ScT[e][d] transposed; see round 5).
// ---------------------------------------------------------------------------
__global__ __launch_bounds__(256) void k_chunk_kv(
    const ushort* __restrict__ Kg, const ushort* __restrict__ Vg,
    ushort* __restrict__ Sst, float* __restrict__ Zst)
{
    __shared__ ushort KcT[64 * 40];   // [d][t] pad 40 -> 2-way LDS (free)
    __shared__ ushort KsT[64 * 40];
    __shared__ ushort VT [64 * 40];   // [e][t]

    const int blk = blockIdx.x;
    const int bh = blk >> 5, g = blk & 31;
    const int b = bh >> 3, h = bh & 7;
    const int tid = threadIdx.x;
    const int rBase = b * T_ + g * C_;
    const int colB = h * DK_;

    {
        int row = tid >> 3, c8 = (tid & 7) * 8;
        float a = (float)(g * C_ + row) * PI_OVER_2T;
        float ca = cosf(a), sa = sinf(a);
        size_t ga = (size_t)(rBase + row) * D_ + colB + c8;
        uint4 kraw = *(const uint4*)&Kg[ga];
        uint4 vraw = *(const uint4*)&Vg[ga];
        const ushort* kp = (const ushort*)&kraw;
        const ushort* vp = (const ushort*)&vraw;
#pragma unroll
        for (int u = 0; u < 8; u++) {
            float kf = bf2f(kp[u]);
            KcT[(c8 + u) * 40 + row] = f2bf(kf * ca);
            KsT[(c8 + u) * 40 + row] = f2bf(kf * sa);
            VT [(c8 + u) * 40 + row] = vp[u];
        }
    }
    __syncthreads();

    if (tid < 128) {
        int d = tid & 63;
        const ushort* src = (tid < 64) ? KcT : KsT;
        float zsum = 0.f;
#pragma unroll
        for (int t = 0; t < C_; t++) zsum += bf2f(src[d * 40 + t]);
        Zst[(size_t)blk * 128 + tid] = zsum;
    }

    const int wave = tid >> 6, lane = tid & 63;
    const int q = lane >> 4, ln = lane & 15;
    s16x8 av = *(const s16x8*)&VT[(wave * 16 + ln) * 40 + q * 8];
    ushort* Sp = Sst + (size_t)blk * 8192;
#pragma unroll
    for (int nj = 0; nj < 4; nj++) {
        s16x8 bc = *(const s16x8*)&KcT[(nj * 16 + ln) * 40 + q * 8];
        s16x8 bs = *(const s16x8*)&KsT[(nj * 16 + ln) * 40 + q * 8];
        f32x4 ac = __builtin_amdgcn_mfma_f32_16x16x32_bf16(
            av, bc, (f32x4){0.f, 0.f, 0.f, 0.f}, 0, 0, 0);
        f32x4 as = __builtin_amdgcn_mfma_f32_16x16x32_bf16(
            av, bs, (f32x4){0.f, 0.f, 0.f, 0.f}, 0, 0, 0);
#pragma unroll
        for (int r = 0; r < 4; r++) {
            int e = wave * 16 + q * 4 + r;
            int d = nj * 16 + ln;
            Sp[e * 64 + d] = f2bf(ac[r]);
            Sp[4096 + e * 64 + d] = f2bf(as[r]);
        }
    }
}

// ---------------------------------------------------------------------------
// Exclusive chunk-scan, LATENCY-PIPELINED: all 32 loads issued independently
// (in flight together), prefix in registers, then independent stores.
// Replaces the 32-step dependent load->store chain (~900 cyc each, ~2
// waves/CU -> ~12 us) with one latency + bandwidth (~3 us).
// ---------------------------------------------------------------------------
__global__ __launch_bounds__(256) void k_scan(
    ushort* __restrict__ Sst, float* __restrict__ Zst)
{
    int id = blockIdx.x * 256 + threadIdx.x;
    if (id < 32768) {
        int bh = id >> 11, i4 = (id & 2047) * 4;
        size_t base = (size_t)bh * (G_ * 8192) + i4;
        ushort4 v[G_];
#pragma unroll
        for (int g = 0; g < G_; g++)
            v[g] = *(const ushort4*)&Sst[base + (size_t)g * 8192];
        float rx = 0.f, ry = 0.f, rz = 0.f, rw = 0.f;
#pragma unroll
        for (int g = 0; g < G_; g++) {
            ushort4 t = v[g];
            ushort4 o;
            o.x = f2bf(rx); o.y = f2bf(ry); o.z = f2bf(rz); o.w = f2bf(rw);
            *(ushort4*)&Sst[base + (size_t)g * 8192] = o;
            rx += bf2f(t.x); ry += bf2f(t.y);
            rz += bf2f(t.z); rw += bf2f(t.w);
        }
    } else {
        int id2 = id - 32768;
        if (id2 >= 512) return;
        int bh = id2 >> 5, i4 = (id2 & 31) * 4;
        size_t base = (size_t)bh * (G_ * 128) + i4;
        float4 v[G_];
#pragma unroll
        for (int g = 0; g < G_; g++)
            v[g] = *(const float4*)&Zst[base + (size_t)g * 128];
        float4 run = make_float4(0.f, 0.f, 0.f, 0.f);
#pragma unroll
        for (int g = 0; g < G_; g++) {
            float4 t = v[g];
            *(float4*)&Zst[base + (size_t)g * 128] = run;
            run.x += t.x; run.y += t.y; run.z += t.z; run.w += t.w;
        }
    }
}

// ---------------------------------------------------------------------------
// Per-chunk output via MFMA (unchanged from round 5).
// ---------------------------------------------------------------------------
__global__ __launch_bounds__(256) void k_out_chunk(
    const ushort* __restrict__ Qg, const ushort* __restrict__ Kg,
    const ushort* __restrict__ Vg, const ushort* __restrict__ Gg,
    const ushort* __restrict__ Sst, const float* __restrict__ Zst,
    ushort* __restrict__ Op)
{
    __shared__ ushort VT[64 * 40];
    __shared__ ushort Pb[32 * 40];
    __shared__ float zinv[32];

    const int blk = blockIdx.x;
    const int bh = blk >> 5, g = blk & 31;
    const int b = bh >> 3, h = bh & 7;
    const int tid = threadIdx.x;
    const int rBase = b * T_ + g * C_;
    const int colB = h * DK_;
    const int wave = tid >> 6, lane = tid & 63;
    const int q = lane >> 4, ln = lane & 15;

    {
        int row = tid >> 3, c8 = (tid & 7) * 8;
        uint4 vraw = *(const uint4*)&Vg[(size_t)(rBase + row) * D_ + colB + c8];
        const ushort* vp = (const ushort*)&vraw;
#pragma unroll
        for (int u = 0; u < 8; u++) VT[(c8 + u) * 40 + row] = vp[u];
    }

    const int mi = wave >> 1, njp = wave & 1;
    const ushort* qrow = Qg + (size_t)(rBase + mi * 16 + ln) * D_ + colB;
    s16x8 aq0 = *(const s16x8*)&qrow[q * 8];
    s16x8 aq1 = *(const s16x8*)&qrow[32 + q * 8];
    {
        const ushort* krow = Kg + (size_t)(rBase + njp * 16 + ln) * D_ + colB;
        s16x8 bk0 = *(const s16x8*)&krow[q * 8];
        s16x8 bk1 = *(const s16x8*)&krow[32 + q * 8];
        f32x4 pacc = __builtin_amdgcn_mfma_f32_16x16x32_bf16(
            aq0, bk0, (f32x4){0.f, 0.f, 0.f, 0.f}, 0, 0, 0);
        pacc = __builtin_amdgcn_mfma_f32_16x16x32_bf16(aq1, bk1, pacc, 0, 0, 0);
        int sl = njp * 16 + ln;
        float as_ = (float)(g * C_ + sl) * PI_OVER_2T;
        float cs_ = cosf(as_), ss_ = sinf(as_);
#pragma unroll
        for (int r = 0; r < 4; r++) {
            int tl = mi * 16 + q * 4 + r;
            float at = (float)(g * C_ + tl) * PI_OVER_2T;
            float w = (sl <= tl) ? (cosf(at) * cs_ + sinf(at) * ss_) : 0.f;
            Pb[tl * 40 + sl] = f2bf(pacc[r] * w);
        }
    }
    __syncthreads();

    {
        int t = tid >> 3, sub = tid & 7;
        uint4 qraw = *(const uint4*)&Qg[(size_t)(rBase + t) * D_ + colB + sub * 8];
        const ushort* qp = (const ushort*)&qraw;
        const float* zcp = Zst + (size_t)blk * 128 + sub * 8;
        float4 zc0 = *(const float4*)&zcp[0];
        float4 zc1 = *(const float4*)&zcp[4];
        float4 zs0 = *(const float4*)&zcp[64];
        float4 zs1 = *(const float4*)&zcp[68];
        float pc = 0.f, ps = 0.f;
        float zcv[8] = {zc0.x, zc0.y, zc0.z, zc0.w, zc1.x, zc1.y, zc1.z, zc1.w};
        float zsv[8] = {zs0.x, zs0.y, zs0.z, zs0.w, zs1.x, zs1.y, zs1.z, zs1.w};
#pragma unroll
        for (int u = 0; u < 8; u++) {
            float qf = bf2f(qp[u]);
            pc += qf * zcv[u]; ps += qf * zsv[u];
        }
        float pr = 0.f;
#pragma unroll
        for (int u = 0; u < 4; u++) pr += bf2f(Pb[t * 40 + sub * 4 + u]);
#pragma unroll
        for (int m = 1; m < 8; m <<= 1) {
            pc += __shfl_xor(pc, m);
            ps += __shfl_xor(ps, m);
            pr += __shfl_xor(pr, m);
        }
        if (sub == 0) {
            float at = (float)(g * C_ + t) * PI_OVER_2T;
            float z = cosf(at) * pc + sinf(at) * ps + pr;
            zinv[t] = 1.f / fmaxf(z, 1e-6f);
        }
    }
    __syncthreads();

    {
        float am = (float)(g * C_ + mi * 16 + ln) * PI_OVER_2T;
        float cm = cosf(am), sm = sinf(am);
        s16x8 aqc0 = bscale(aq0, cm), aqc1 = bscale(aq1, cm);
        s16x8 aqs0 = bscale(aq0, sm), aqs1 = bscale(aq1, sm);
        s16x8 pf = *(const s16x8*)&Pb[(mi * 16 + ln) * 40 + q * 8];
        const ushort* Sp = Sst + (size_t)blk * 8192;
#pragma unroll
        for (int jj = 0; jj < 2; jj++) {
            int nj = 2 * (wave & 1) + jj;
            const ushort* scp = Sp + (nj * 16 + ln) * 64;
            s16x8 bc0 = *(const s16x8*)&scp[q * 8];
            s16x8 bc1 = *(const s16x8*)&scp[32 + q * 8];
            s16x8 bs0 = *(const s16x8*)&scp[4096 + q * 8];
            s16x8 bs1 = *(const s16x8*)&scp[4096 + 32 + q * 8];
            s16x8 bv  = *(const s16x8*)&VT[(nj * 16 + ln) * 40 + q * 8];
            f32x4 acc = __builtin_amdgcn_mfma_f32_16x16x32_bf16(
                pf, bv, (f32x4){0.f, 0.f, 0.f, 0.f}, 0, 0, 0);
            acc = __builtin_amdgcn_mfma_f32_16x16x32_bf16(aqc0, bc0, acc, 0, 0, 0);
            acc = __builtin_amdgcn_mfma_f32_16x16x32_bf16(aqc1, bc1, acc, 0, 0, 0);
            acc = __builtin_amdgcn_mfma_f32_16x16x32_bf16(aqs0, bs0, acc, 0, 0, 0);
            acc = __builtin_amdgcn_mfma_f32_16x16x32_bf16(aqs1, bs1, acc, 0, 0, 0);
#pragma unroll
            for (int r = 0; r < 4; r++) {
                int tl = mi * 16 + q * 4 + r;
                int e = nj * 16 + ln;
                size_t go = (size_t)(rBase + tl) * D_ + colB + e;
                float o = acc[r] * zinv[tl] * bf2f(Gg[go]);
                Op[go] = f2bf(o);
            }
        }
    }
}

// ---------------------------------------------------------------------------
extern "C" void kernel_launch(void* const* d_in, const int* in_sizes, int n_in,
                              void* d_out, int out_size, void* d_ws, size_t ws_size,
                              hipStream_t stream)
{
    const float* x  = (const float*)d_in[0];
    const float* Wq = (const float*)d_in[1];
    const float* Wk = (const float*)d_in[2];
    const float* Wv = (const float*)d_in[3];
    const float* Wo = (const float*)d_in[4];
    const float* Wg = (const float*)d_in[5];
    const float* bg = (const float*)d_in[6];
    float* out = (float*)d_out;

    ushort* wsu = (ushort*)d_ws;
    ushort* xb    = wsu;                   // 1M bf16
    ushort* WtAll = xb + 1048576;          // 5*256K bf16
    ushort* Qg    = WtAll + 1310720;       // 1M bf16 each
    ushort* Kg    = Qg + 1048576;
    ushort* Vg    = Kg + 1048576;
    ushort* Gg    = Vg + 1048576;
    ushort* Sst   = Gg + 1048576;          // 4M bf16 (ScT/SsT per chunk)
    ushort* Opb   = Sst + 4194304;         // 1M bf16
    float*  Zst   = (float*)(Opb + 1048576);  // 64K f32

    dim3 blk(256);
    k_conv<<<dim3(1344), blk, 0, stream>>>(x, Wq, Wk, Wv, Wg, Wo, xb, WtAll);
    k_gemm<0, 128, 64, 64><<<dim3(32, 16), blk, 0, stream>>>(
        xb, WtAll, bg, Qg, Kg, Vg, Gg);
    k_chunk_kv<<<dim3(NBH_ * G_), blk, 0, stream>>>(Kg, Vg, Sst, Zst);
    k_scan<<<dim3(130), blk, 0, stream>>>(Sst, Zst);
    k_out_chunk<<<dim3(NBH_ * G_), blk, 0, stream>>>(
        Qg, Kg, Vg, Gg, Sst, Zst, Opb);
    k_gemm<1, 64, 64, 64><<<dim3(8, 32), blk, 0, stream>>>(
        Opb, WtAll + (size_t)4 * 262144, nullptr, out, nullptr, nullptr, nullptr);
}